// Round 8
// baseline (10419.350 us; speedup 1.0000x reference)
//
#include <hip/hip_runtime.h>
#include <stdint.h>

#define F_DIM 512
#define MAXV  9216
#define WSZ   1024
#define LCAP  32

typedef unsigned long long u64;

// ---------------- per-vertex squared norm (fp64 accumulate) ----------------
__global__ void k_sq(const float* __restrict__ img, double* __restrict__ sqd, int V) {
  int v = blockIdx.x;
  if (v >= V) return;
  const float* row = img + (size_t)v * F_DIM;
  double s = 0.0;
  for (int f = threadIdx.x; f < F_DIM; f += 64) {
    double x = (double)row[f];
    s += x * x;
  }
  for (int off = 32; off > 0; off >>= 1) s += __shfl_down(s, off);
  if (threadIdx.x == 0) sqd[v] = s;
}

// ---------------- edge eligibility (boundary test) -------------------------
__global__ void k_prep(const float* __restrict__ vs, const int* __restrict__ edges,
                       int E, unsigned char* __restrict__ elig) {
  int i = blockIdx.x * blockDim.x + threadIdx.x;
  if (i < E) {
    int a = edges[i], b = edges[E + i];
    float ax = vs[2 * a], ay = vs[2 * a + 1];
    float bx = vs[2 * b], by = vs[2 * b + 1];
    const float eps = 1e-3f;
    const float hi = 1.0f - 1e-3f;
    bool ba = (ax < eps) || (ax > hi) || (ay < eps) || (ay > hi);
    bool bb = (bx < eps) || (bx > hi) || (by < eps) || (by > hi);
    elig[i] = (!ba && !bb) ? 1 : 0;
  }
}

// ---------------- sortable keys: prio(double) top bits | edge id -----------
__global__ void k_keys(const double* __restrict__ sqd, const int* __restrict__ edges,
                       int E, int P, u64* __restrict__ keys) {
  int e = blockIdx.x * blockDim.x + threadIdx.x;
  if (e >= P) return;
  if (e < E) {
    double prio = sqd[edges[e]] + sqd[edges[E + e]];
    u64 bits = (u64)__double_as_longlong(prio);
    keys[e] = (bits & ~0xFFFFull) | (u64)e;
  } else {
    keys[e] = ~0ull;
  }
}

// ---------------- single-block bitonic sort, LDS-staged --------------------
#define SCH 4096
__global__ void __launch_bounds__(1024)
k_sort(u64* __restrict__ keys, int n) {
  __shared__ u64 buf[SCH];
  int tid = threadIdx.x;
  int nt = blockDim.x;
  int ch = n < SCH ? n : SCH;
  for (int chunk = 0; chunk < n; chunk += ch) {
    for (int i = tid; i < ch; i += nt) buf[i] = keys[chunk + i];
    __syncthreads();
    for (int k = 2; k <= ch; k <<= 1) {
      for (int j = k >> 1; j > 0; j >>= 1) {
        for (int li = tid; li < ch; li += nt) {
          int lj = li ^ j;
          if (lj > li) {
            u64 x = buf[li], y = buf[lj];
            bool up = (((chunk + li) & k) == 0);
            if (up ? (x > y) : (x < y)) { buf[li] = y; buf[lj] = x; }
          }
        }
        __syncthreads();
      }
    }
    for (int i = tid; i < ch; i += nt) keys[chunk + i] = buf[i];
    __syncthreads();
  }
  for (int k = (ch << 1); k <= n; k <<= 1) {
    for (int j = k >> 1; j >= ch; j >>= 1) {
      for (int i = tid; i < n; i += nt) {
        int ixj = i ^ j;
        if (ixj > i) {
          u64 x = keys[i], y = keys[ixj];
          bool up = ((i & k) == 0);
          if (up ? (x > y) : (x < y)) { keys[i] = y; keys[ixj] = x; }
        }
      }
      __syncthreads();
    }
    for (int chunk = 0; chunk < n; chunk += ch) {
      for (int i = tid; i < ch; i += nt) buf[i] = keys[chunk + i];
      __syncthreads();
      for (int j = ch >> 1; j > 0; j >>= 1) {
        for (int li = tid; li < ch; li += nt) {
          int lj = li ^ j;
          if (lj > li) {
            u64 x = buf[li], y = buf[lj];
            bool up = (((chunk + li) & k) == 0);
            if (up ? (x > y) : (x < y)) { buf[li] = y; buf[lj] = x; }
          }
        }
        __syncthreads();
      }
      for (int i = tid; i < ch; i += nt) keys[chunk + i] = buf[i];
      __syncthreads();
    }
  }
}

// ---------------- gather sorted (v0,v1,elig) into one packed word ----------
__global__ void k_reorder(const u64* __restrict__ keys, const int* __restrict__ edges,
                          const unsigned char* __restrict__ elig, int E,
                          unsigned* __restrict__ packed) {
  int t = blockIdx.x * blockDim.x + threadIdx.x;
  if (t >= E) return;
  int eid = (int)(keys[t] & 0xFFFFull);
  unsigned v0 = (unsigned)edges[eid];
  unsigned v1 = (unsigned)edges[E + eid];
  unsigned el = (unsigned)elig[eid];
  packed[t] = v0 | (v1 << 14) | (el << 28);
}

// ---------------- generic zero ---------------------------------------------
__global__ void k_zero32(unsigned* __restrict__ p, int n) {
  int i = blockIdx.x * blockDim.x + threadIdx.x;
  if (i < n) p[i] = 0u;
}

// ---------------- build adjacency bitsets + summaries ----------------------
__global__ void k_bs_build(const int* __restrict__ edges, int E,
                           unsigned* __restrict__ bs, unsigned* __restrict__ summ) {
  int e = blockIdx.x * blockDim.x + threadIdx.x;
  if (e >= E) return;
  int a = edges[e], b = edges[E + e];
  atomicOr(bs + (size_t)a * 512 + (b >> 5), 1u << (b & 31));
  atomicOr(bs + (size_t)b * 512 + (a >> 5), 1u << (a & 31));
  atomicOr(summ + (size_t)a * 16 + ((b >> 5) >> 5), 1u << ((b >> 5) & 31));
  atomicOr(summ + (size_t)b * 16 + ((a >> 5) >> 5), 1u << ((a >> 5) & 31));
}

// ---------------- windowed deterministic-reservation decimation ------------
// Sliding window of WSZ sorted slots; per round: (A) undecided slots reserve
// Eres/V1res maps; (B) touched/entrant slots refresh (bitset eval via
// summaries + extract neighbor lists); (C) slots with no smaller undecided
// conflictor finalize (accept/reject); (D) accepted commit in parallel
// (commutative bit atomics); (E) slide. Decisions for slots before the
// sequential stop point are exact; extra commits are dropped in compaction.
__global__ void __launch_bounds__(1024, 1)
k_pardec(int E, int V, int acceptTarget, const unsigned* __restrict__ packed,
         volatile unsigned* bs, volatile unsigned* summ,
         unsigned char* __restrict__ aflag, unsigned short* __restrict__ av0g,
         unsigned short* __restrict__ av1g,
         volatile unsigned short* wl0, volatile unsigned short* wl1) {
  __shared__ unsigned Eres[MAXV];
  __shared__ unsigned V1res[MAXV];
  __shared__ unsigned aliveb[MAXV / 32];
  __shared__ unsigned touched[MAXV / 32];
  __shared__ unsigned char stat[WSZ];     // 0 undec, 1 decided-rej, 2 decided-acc
  __shared__ unsigned char needR[WSZ];
  __shared__ unsigned char tentf[WSZ];    // bit0 tent-accept, bit1 bigW
  __shared__ unsigned char n0c[WSZ];
  __shared__ unsigned char n1c[WSZ];
  __shared__ unsigned short sv0[WSZ], sv1[WSZ];
  __shared__ int sabs[WSZ];
  __shared__ unsigned short rque[WSZ];
  __shared__ unsigned short cque[WSZ];
  __shared__ int rqn, cqn, minU, advSh, Psh, winEndSh, acceptPrefix, doneF;
  __shared__ int exc[16][2];

  const int tid = threadIdx.x;
  const int wv = tid >> 6, lane = tid & 63;
  if (V > MAXV) return;

  for (int i = tid; i < MAXV / 32; i += 1024) { aliveb[i] = 0xFFFFFFFFu; touched[i] = 0u; }
  if (tid == 0) {
    Psh = 0; winEndSh = (E < WSZ) ? E : WSZ; acceptPrefix = 0; doneF = 0;
  }
  __syncthreads();
  {
    int we = winEndSh;
    if (tid < we) {
      unsigned pk = packed[tid];
      sv0[tid] = (unsigned short)(pk & 0x3FFFu);
      sv1[tid] = (unsigned short)((pk >> 14) & 0x3FFFu);
      sabs[tid] = tid;
      stat[tid] = ((pk >> 28) & 1u) ? 0 : 1;
      needR[tid] = 1; tentf[tid] = 0;
    } else if (tid < WSZ) {
      stat[tid] = 1; sabs[tid] = -(1 << 29); needR[tid] = 0;
    }
  }
  __syncthreads();

  for (int round = 0; round < 60000; ++round) {
    const int P = Psh;
    const int winEnd = winEndSh;
    // ---- A: reset maps, reservations, refresh queue, min undecided ----
    for (int i = tid; i < MAXV; i += 1024) { Eres[i] = 0xFFFFFFFFu; V1res[i] = 0xFFFFFFFFu; }
    if (tid == 0) { rqn = 0; cqn = 0; minU = 1 << 30; }
    __syncthreads();
    {
      int c = tid;
      if (stat[c] == 0) {
        int r = sabs[c] - P;
        atomicMin(&Eres[sv0[c]], (unsigned)r);
        atomicMin(&Eres[sv1[c]], (unsigned)r);
        atomicMin(&V1res[sv1[c]], (unsigned)r);
        atomicMin(&minU, r);
        if (needR[c]) { int q = atomicAdd(&rqn, 1); rque[q] = (unsigned short)c; }
      }
    }
    __syncthreads();
    // ---- B: refresh (wave-cooperative) ----
    for (int qi = wv; qi < rqn; qi += 16) {
      int c = rque[qi];
      int v0 = sv0[c], v1 = sv1[c];
      bool a0 = (aliveb[v0 >> 5] >> (v0 & 31)) & 1;
      bool a1 = (aliveb[v1 >> 5] >> (v1 & 31)) & 1;
      if (!a0 || !a1) { if (lane == 0) { stat[c] = 1; needR[c] = 0; } continue; }
      int d = lane & 15, q = lane >> 4;
      unsigned sd0 = summ[(size_t)v0 * 16 + d];
      unsigned sd1 = summ[(size_t)v1 * 16 + d];
      if (lane == 0) { exc[wv][0] = 0; exc[wv][1] = 0; }
      asm volatile("s_waitcnt lgkmcnt(0)" ::: "memory");
      __builtin_amdgcn_sched_barrier(0);
      // |N(v0) & N(v1)| over candidate dwords
      int p = 0;
      unsigned m = sd0 & sd1;
      while (m) {
        int b = __builtin_ctz(m); m &= m - 1;
        if ((b & 3) != q) continue;
        int dw = d * 32 + b;
        p += __popc(bs[(size_t)v0 * 512 + dw] & bs[(size_t)v1 * 512 + dw]);
      }
      for (int off = 1; off < 64; off <<= 1) p += __shfl_xor(p, off);
      // extract N(v0), N(v1) lists (order irrelevant)
      m = sd0;
      while (m) {
        int b = __builtin_ctz(m); m &= m - 1;
        if ((b & 3) != q) continue;
        int dw = d * 32 + b;
        unsigned w = bs[(size_t)v0 * 512 + dw];
        while (w) {
          int bb = __builtin_ctz(w); w &= w - 1;
          int pos = atomicAdd(&exc[wv][0], 1);
          if (pos < LCAP) wl0[c * LCAP + pos] = (unsigned short)(dw * 32 + bb);
        }
      }
      m = sd1;
      while (m) {
        int b = __builtin_ctz(m); m &= m - 1;
        if ((b & 3) != q) continue;
        int dw = d * 32 + b;
        unsigned w = bs[(size_t)v1 * 512 + dw];
        while (w) {
          int bb = __builtin_ctz(w); w &= w - 1;
          int pos = atomicAdd(&exc[wv][1], 1);
          if (pos < LCAP) wl1[c * LCAP + pos] = (unsigned short)(dw * 32 + bb);
        }
      }
      asm volatile("s_waitcnt lgkmcnt(0)" ::: "memory");
      __builtin_amdgcn_sched_barrier(0);
      if (lane == 0) {
        int n0 = exc[wv][0], n1 = exc[wv][1];
        unsigned tf = (p == 2) ? 1u : 0u;
        if (n0 > LCAP || n1 > LCAP) tf |= 2u;
        n0c[c] = (unsigned char)(n0 < LCAP ? n0 : LCAP);
        n1c[c] = (unsigned char)(n1 < LCAP ? n1 : LCAP);
        tentf[c] = (unsigned char)tf;
        needR[c] = 0;
      }
    }
    asm volatile("s_waitcnt vmcnt(0)" ::: "memory");
    __syncthreads();
    // ---- C: finalize ----
    {
      int c = tid;
      if (stat[c] == 0 && !needR[c]) {
        int r = sabs[c] - P;
        int v0 = sv0[c], v1 = sv1[c];
        bool blocked = false;
        if (tentf[c] & 2) {
          blocked = (r != minU);
        } else if (Eres[v0] < (unsigned)r || Eres[v1] < (unsigned)r) {
          blocked = true;
        } else {
          int n0 = n0c[c], n1 = n1c[c];
          for (int i = 0; i < n0 && !blocked; ++i) {
            int x = wl0[c * LCAP + i];
            if (V1res[x] < (unsigned)r) blocked = true;
          }
          for (int i = 0; i < n1 && !blocked; ++i) {
            int u = wl1[c * LCAP + i];
            if (V1res[u] < (unsigned)r || Eres[u] < (unsigned)r) blocked = true;
          }
        }
        if (!blocked) {
          if (tentf[c] & 1) {
            stat[c] = 2;
            int qq = atomicAdd(&cqn, 1);
            cque[qq] = (unsigned short)c;
          } else {
            stat[c] = 1;
          }
        }
      }
    }
    __syncthreads();
    // ---- D: commits (wave-cooperative, mutually non-interfering) ----
    for (int qi = wv; qi < cqn; qi += 16) {
      int c = cque[qi];
      int v0 = sv0[c], v1 = sv1[c], abss = sabs[c];
      int d = lane & 15, q = lane >> 4;
      unsigned sd0 = summ[(size_t)v0 * 16 + d];
      unsigned sd1 = summ[(size_t)v1 * 16 + d];
      unsigned un = sd0 | sd1;
      unsigned m = un;
      while (m) {
        int b = __builtin_ctz(m); m &= m - 1;
        if ((b & 3) != q) continue;
        int dw = d * 32 + b;
        unsigned mw = bs[(size_t)v0 * 512 + dw] | bs[(size_t)v1 * 512 + dw];
        if (dw == (v0 >> 5)) mw &= ~(1u << (v0 & 31));
        if (dw == (v1 >> 5)) mw &= ~(1u << (v1 & 31));
        bs[(size_t)v0 * 512 + dw] = mw;
      }
      if (lane < 16) summ[(size_t)v0 * 16 + lane] = un;
      int w0d = v0 >> 5; unsigned b0m = 1u << (v0 & 31);
      int w1d = v1 >> 5; unsigned b1m = ~(1u << (v1 & 31));
      unsigned sb0 = 1u << (w0d & 31); int sw0 = w0d >> 5;
      m = sd1;
      while (m) {
        int b = __builtin_ctz(m); m &= m - 1;
        if ((b & 3) != q) continue;
        int dw = d * 32 + b;
        unsigned w = bs[(size_t)v1 * 512 + dw];
        while (w) {
          int bb = __builtin_ctz(w); w &= w - 1;
          int u = dw * 32 + bb;
          if (u == v0) continue;
          atomicAnd((unsigned*)&bs[(size_t)u * 512 + w1d], b1m);
          atomicOr((unsigned*)&bs[(size_t)u * 512 + w0d], b0m);
          atomicOr((unsigned*)&summ[(size_t)u * 16 + sw0], sb0);
          atomicOr(&touched[u >> 5], 1u << (u & 31));
        }
      }
      if (lane == 0) {
        atomicAnd(&aliveb[v1 >> 5], ~(1u << (v1 & 31)));
        atomicOr(&touched[v0 >> 5], 1u << (v0 & 31));
        atomicOr(&touched[v1 >> 5], 1u << (v1 & 31));
        aflag[abss] = 1;
        av0g[abss] = (unsigned short)v0;
        av1g[abss] = (unsigned short)v1;
      }
    }
    asm volatile("s_waitcnt vmcnt(0)" ::: "memory");
    __syncthreads();
    // ---- E: mark refresh needs, advance, slide ----
    if (tid == 0) minU = 1 << 30;
    __syncthreads();
    {
      int c = tid;
      if (stat[c] == 0) {
        int v0 = sv0[c], v1 = sv1[c];
        if (((touched[v0 >> 5] >> (v0 & 31)) & 1) ||
            ((touched[v1 >> 5] >> (v1 & 31)) & 1)) needR[c] = 1;
        atomicMin(&minU, sabs[c] - P);
      }
    }
    __syncthreads();
    if (tid == 0) {
      advSh = (minU >= (1 << 29)) ? (winEnd - P) : minU;
    }
    __syncthreads();
    int adv = advSh;
    {
      int c = tid;
      int r = sabs[c] - P;
      if (r >= 0 && r < adv && stat[c] == 2) atomicAdd(&acceptPrefix, 1);
    }
    for (int i = tid; i < MAXV / 32; i += 1024) touched[i] = 0u;
    __syncthreads();
    if (tid == 0) {
      int nP = P + adv;
      int nEnd = nP + WSZ; if (nEnd > E) nEnd = E;
      Psh = nP;
      advSh = winEnd;           // pass old end
      winEndSh = nEnd;
      if (acceptPrefix >= acceptTarget || nP >= E) doneF = 1;
    }
    __syncthreads();
    {
      int oldEnd = advSh, nEnd = winEndSh;
      int i = oldEnd + tid;
      if (i < nEnd) {
        int c = i & (WSZ - 1);
        unsigned pk = packed[i];
        sv0[c] = (unsigned short)(pk & 0x3FFFu);
        sv1[c] = (unsigned short)((pk >> 14) & 0x3FFFu);
        sabs[c] = i;
        stat[c] = ((pk >> 28) & 1u) ? 0 : 1;
        needR[c] = 1; tentf[c] = 0;
      }
    }
    __syncthreads();
    if (doneF) break;
  }
}

// ---------------- compact accepts (slot order), cap at target --------------
__global__ void __launch_bounds__(1024)
k_compact(const unsigned char* __restrict__ aflag, const unsigned short* __restrict__ av0,
          const unsigned short* __restrict__ av1, int E, int target,
          int2* __restrict__ events, int* __restrict__ nev_out) {
  __shared__ int woff[16];
  __shared__ int runsh;
  int tid = threadIdx.x, wv = tid >> 6, lane = tid & 63;
  if (tid == 0) runsh = 0;
  __syncthreads();
  for (int base = 0; base < E; base += 1024) {
    int i = base + tid;
    int f = (i < E) ? aflag[i] : 0;
    u64 b = __ballot(f != 0);
    u64 below = (lane == 0) ? 0ull : (~0ull >> (64 - lane));
    int myr = __popcll(b & below);
    if (lane == 0) woff[wv] = __popcll(b);
    __syncthreads();
    if (tid == 0) {
      int s = runsh;
      for (int k = 0; k < 16; ++k) { int t = woff[k]; woff[k] = s; s += t; }
      runsh = s;
    }
    __syncthreads();
    if (f) {
      int pos = woff[wv] + myr;
      if (pos < target) events[pos] = make_int2((int)av0[i], (int)av1[i]);
    }
    __syncthreads();
  }
  if (tid == 0) nev_out[0] = runsh < target ? runsh : target;
}

// ---------------- reverse-replay: owner + weight per original vertex -------
__global__ void __launch_bounds__(256)
k_weights(const int2* __restrict__ events, const int* __restrict__ nev_p,
          int V, int* __restrict__ own, float* __restrict__ wgt) {
  __shared__ int O[MAXV];
  __shared__ unsigned short H[MAXV];
  __shared__ int2 evb[256];
  int tid = threadIdx.x;
  if (V > MAXV) return;
  for (int v = tid; v < V; v += blockDim.x) { O[v] = v; H[v] = 0; }
  int n = nev_p[0];
  __syncthreads();
  int nb = (n + 255) >> 8;
  for (int b = nb - 1; b >= 0; --b) {
    int bbase = b << 8;
    int cnt = n - bbase; if (cnt > 256) cnt = 256;
    if (tid < cnt) evb[tid] = events[bbase + tid];
    __syncthreads();
    if (tid == 0) {
      for (int k = cnt - 1; k >= 0; --k) {
        int2 ev = evb[k];
        int h = (int)H[ev.x] + 1;
        H[ev.x] = (unsigned short)h;
        H[ev.y] = (unsigned short)h;
        O[ev.y] = O[ev.x];
      }
    }
    __syncthreads();
  }
  for (int v = tid; v < V; v += blockDim.x) {
    own[v] = O[v];
    wgt[v] = ldexpf(1.0f, -(int)H[v]);
  }
}

// ---------------- output ---------------------------------------------------
__global__ void k_scatter(const float* __restrict__ img, const int* __restrict__ own,
                          const float* __restrict__ wgt, float* __restrict__ out, int V) {
  int v = blockIdx.x;
  if (v >= V) return;
  float w = wgt[v];
  int o = own[v];
  const float* src = img + (size_t)v * F_DIM;
  float* dst = out + (size_t)o * F_DIM;
  if (w == 1.0f) {
    for (int f = threadIdx.x; f < F_DIM; f += blockDim.x) dst[f] = src[f];
  } else {
    for (int f = threadIdx.x; f < F_DIM; f += blockDim.x) atomicAdd(&dst[f], w * src[f]);
  }
}

extern "C" void kernel_launch(void* const* d_in, const int* in_sizes, int n_in,
                              void* d_out, int out_size, void* d_ws, size_t ws_size,
                              hipStream_t stream) {
  const float* img  = (const float*)d_in[0];
  const int* edges  = (const int*)d_in[1];
  const float* vs   = (const float*)d_in[2];
  int V = in_sizes[2] / 2;
  int E = in_sizes[1] / 2;
  int P = 1; while (P < E) P <<= 1;

  char* wsp = (char*)d_ws;
  size_t off = 0;
  auto alloc = [&](size_t bytes) -> void* {
    void* p = (void*)(wsp + off);
    off = (off + bytes + 255) & ~(size_t)255;
    return p;
  };
  double* sqd          = (double*)alloc((size_t)V * 8);
  u64* keys            = (u64*)alloc((size_t)P * 8);
  unsigned char* elig  = (unsigned char*)alloc((size_t)E);
  unsigned* packed     = (unsigned*)alloc((size_t)E * 4);
  unsigned* summ       = (unsigned*)alloc((size_t)V * 16 * 4);
  unsigned char* aflag = (unsigned char*)alloc((size_t)E + 4);
  unsigned short* av0  = (unsigned short*)alloc((size_t)E * 2);
  unsigned short* av1  = (unsigned short*)alloc((size_t)E * 2);
  unsigned short* wl0  = (unsigned short*)alloc((size_t)WSZ * LCAP * 2);
  unsigned short* wl1  = (unsigned short*)alloc((size_t)WSZ * LCAP * 2);
  int2* events         = (int2*)alloc((size_t)(V / 2 + 64) * 8);
  int* nev             = (int*)alloc(256);
  int* own             = (int*)alloc((size_t)V * 4);
  float* wgt           = (float*)alloc((size_t)V * 4);

  unsigned* bs = (unsigned*)d_out;   // 9216 rows x 2048B == out buffer exactly
  int n4 = V * F_DIM;                // dwords in d_out
  int acceptTarget = V - V / 2;

  hipLaunchKernelGGL(k_sq, dim3(V), dim3(64), 0, stream, img, sqd, V);
  hipLaunchKernelGGL(k_prep, dim3((E + 255) / 256), dim3(256), 0, stream, vs, edges, E, elig);
  hipLaunchKernelGGL(k_keys, dim3((P + 255) / 256), dim3(256), 0, stream, sqd, edges, E, P, keys);
  hipLaunchKernelGGL(k_sort, dim3(1), dim3(1024), 0, stream, keys, P);
  hipLaunchKernelGGL(k_reorder, dim3((E + 255) / 256), dim3(256), 0, stream, keys, edges, elig, E, packed);
  hipLaunchKernelGGL(k_zero32, dim3((n4 + 255) / 256), dim3(256), 0, stream, bs, n4);
  int nsum = V * 16;
  hipLaunchKernelGGL(k_zero32, dim3((nsum + 255) / 256), dim3(256), 0, stream, summ, nsum);
  int nafl = (E + 7) / 4;
  hipLaunchKernelGGL(k_zero32, dim3((nafl + 255) / 256), dim3(256), 0, stream, (unsigned*)aflag, nafl);
  hipLaunchKernelGGL(k_bs_build, dim3((E + 255) / 256), dim3(256), 0, stream, edges, E, bs, summ);
  hipLaunchKernelGGL(k_pardec, dim3(1), dim3(1024), 0, stream,
                     E, V, acceptTarget, packed,
                     (volatile unsigned*)bs, (volatile unsigned*)summ,
                     aflag, av0, av1,
                     (volatile unsigned short*)wl0, (volatile unsigned short*)wl1);
  hipLaunchKernelGGL(k_compact, dim3(1), dim3(1024), 0, stream, aflag, av0, av1, E, acceptTarget, events, nev);
  hipLaunchKernelGGL(k_weights, dim3(1), dim3(256), 0, stream, events, nev, V, own, wgt);
  hipLaunchKernelGGL(k_zero32, dim3((n4 + 255) / 256), dim3(256), 0, stream, (unsigned*)d_out, n4);
  hipLaunchKernelGGL(k_scatter, dim3(V), dim3(256), 0, stream, img, own, wgt, (float*)d_out, V);
}

// Round 9
// 10015.966 us; speedup vs baseline: 1.0403x; 1.0403x over previous
//
#include <hip/hip_runtime.h>
#include <stdint.h>

#define F_DIM 512
#define MAXV  9216
#define WSZ   1024
#define LCAP  32

typedef unsigned long long u64;

// ---------------- per-vertex squared norm (fp64 accumulate) ----------------
__global__ void k_sq(const float* __restrict__ img, double* __restrict__ sqd, int V) {
  int v = blockIdx.x;
  if (v >= V) return;
  const float* row = img + (size_t)v * F_DIM;
  double s = 0.0;
  for (int f = threadIdx.x; f < F_DIM; f += 64) {
    double x = (double)row[f];
    s += x * x;
  }
  for (int off = 32; off > 0; off >>= 1) s += __shfl_down(s, off);
  if (threadIdx.x == 0) sqd[v] = s;
}

// ---------------- edge eligibility (boundary test) -------------------------
__global__ void k_prep(const float* __restrict__ vs, const int* __restrict__ edges,
                       int E, unsigned char* __restrict__ elig) {
  int i = blockIdx.x * blockDim.x + threadIdx.x;
  if (i < E) {
    int a = edges[i], b = edges[E + i];
    float ax = vs[2 * a], ay = vs[2 * a + 1];
    float bx = vs[2 * b], by = vs[2 * b + 1];
    const float eps = 1e-3f;
    const float hi = 1.0f - 1e-3f;
    bool ba = (ax < eps) || (ax > hi) || (ay < eps) || (ay > hi);
    bool bb = (bx < eps) || (bx > hi) || (by < eps) || (by > hi);
    elig[i] = (!ba && !bb) ? 1 : 0;
  }
}

// ---------------- sortable keys: prio(double) top bits | edge id -----------
__global__ void k_keys(const double* __restrict__ sqd, const int* __restrict__ edges,
                       int E, int P, u64* __restrict__ keys) {
  int e = blockIdx.x * blockDim.x + threadIdx.x;
  if (e >= P) return;
  if (e < E) {
    double prio = sqd[edges[e]] + sqd[edges[E + e]];
    u64 bits = (u64)__double_as_longlong(prio);
    keys[e] = (bits & ~0xFFFFull) | (u64)e;
  } else {
    keys[e] = ~0ull;
  }
}

// ---------------- single-block bitonic sort, LDS-staged --------------------
#define SCH 4096
__global__ void __launch_bounds__(1024)
k_sort(u64* __restrict__ keys, int n) {
  __shared__ u64 buf[SCH];
  int tid = threadIdx.x;
  int nt = blockDim.x;
  int ch = n < SCH ? n : SCH;
  for (int chunk = 0; chunk < n; chunk += ch) {
    for (int i = tid; i < ch; i += nt) buf[i] = keys[chunk + i];
    __syncthreads();
    for (int k = 2; k <= ch; k <<= 1) {
      for (int j = k >> 1; j > 0; j >>= 1) {
        for (int li = tid; li < ch; li += nt) {
          int lj = li ^ j;
          if (lj > li) {
            u64 x = buf[li], y = buf[lj];
            bool up = (((chunk + li) & k) == 0);
            if (up ? (x > y) : (x < y)) { buf[li] = y; buf[lj] = x; }
          }
        }
        __syncthreads();
      }
    }
    for (int i = tid; i < ch; i += nt) keys[chunk + i] = buf[i];
    __syncthreads();
  }
  for (int k = (ch << 1); k <= n; k <<= 1) {
    for (int j = k >> 1; j >= ch; j >>= 1) {
      for (int i = tid; i < n; i += nt) {
        int ixj = i ^ j;
        if (ixj > i) {
          u64 x = keys[i], y = keys[ixj];
          bool up = ((i & k) == 0);
          if (up ? (x > y) : (x < y)) { keys[i] = y; keys[ixj] = x; }
        }
      }
      __syncthreads();
    }
    for (int chunk = 0; chunk < n; chunk += ch) {
      for (int i = tid; i < ch; i += nt) buf[i] = keys[chunk + i];
      __syncthreads();
      for (int j = ch >> 1; j > 0; j >>= 1) {
        for (int li = tid; li < ch; li += nt) {
          int lj = li ^ j;
          if (lj > li) {
            u64 x = buf[li], y = buf[lj];
            bool up = (((chunk + li) & k) == 0);
            if (up ? (x > y) : (x < y)) { buf[li] = y; buf[lj] = x; }
          }
        }
        __syncthreads();
      }
      for (int i = tid; i < ch; i += nt) keys[chunk + i] = buf[i];
      __syncthreads();
    }
  }
}

// ---------------- gather sorted (v0,v1,elig) into one packed word ----------
__global__ void k_reorder(const u64* __restrict__ keys, const int* __restrict__ edges,
                          const unsigned char* __restrict__ elig, int E,
                          unsigned* __restrict__ packed) {
  int t = blockIdx.x * blockDim.x + threadIdx.x;
  if (t >= E) return;
  int eid = (int)(keys[t] & 0xFFFFull);
  unsigned v0 = (unsigned)edges[eid];
  unsigned v1 = (unsigned)edges[E + eid];
  unsigned el = (unsigned)elig[eid];
  packed[t] = v0 | (v1 << 14) | (el << 28);
}

// ---------------- generic zero ---------------------------------------------
__global__ void k_zero32(unsigned* __restrict__ p, int n) {
  int i = blockIdx.x * blockDim.x + threadIdx.x;
  if (i < n) p[i] = 0u;
}

// ---------------- build adjacency bitsets + summaries ----------------------
__global__ void k_bs_build(const int* __restrict__ edges, int E,
                           unsigned* __restrict__ bs, unsigned* __restrict__ summ) {
  int e = blockIdx.x * blockDim.x + threadIdx.x;
  if (e >= E) return;
  int a = edges[e], b = edges[E + e];
  atomicOr(bs + (size_t)a * 512 + (b >> 5), 1u << (b & 31));
  atomicOr(bs + (size_t)b * 512 + (a >> 5), 1u << (a & 31));
  atomicOr(summ + (size_t)a * 16 + ((b >> 5) >> 5), 1u << ((b >> 5) & 31));
  atomicOr(summ + (size_t)b * 16 + ((a >> 5) >> 5), 1u << ((a >> 5) & 31));
}

// ---------------- windowed deterministic-reservation decimation ------------
// v2: thread-per-candidate refresh + inner LDS-only decision cascade.
// Pending accepts (stat=2) keep reserving Eres/V1res until committed, so
// batched commits remain mutually non-interfering (same invariants as R8).
__global__ void __launch_bounds__(1024, 1)
k_pardec(int E, int V, int acceptTarget, const unsigned* __restrict__ packed,
         volatile unsigned* bs, volatile unsigned* summ,
         unsigned char* __restrict__ aflag, unsigned short* __restrict__ av0g,
         unsigned short* __restrict__ av1g,
         volatile unsigned short* wl0, volatile unsigned short* wl1) {
  __shared__ unsigned Eres[MAXV];
  __shared__ unsigned V1res[MAXV];
  __shared__ unsigned aliveb[MAXV / 32];
  __shared__ unsigned touchb[MAXV / 32];
  __shared__ unsigned char stat[WSZ];     // 0 undec, 1 rej, 2 acc-pending, 3 acc-committed
  __shared__ unsigned char needR[WSZ];
  __shared__ unsigned char tentf[WSZ];    // bit0 tent-accept, bit1 bigW
  __shared__ unsigned char n0c[WSZ], n1c[WSZ];
  __shared__ unsigned short sv0[WSZ], sv1[WSZ];
  __shared__ int sabs[WSZ];
  __shared__ unsigned short rque[WSZ], cque[WSZ];
  __shared__ int rqn, cqn, minRes, minU, progress, allDirty;
  __shared__ int Psh, winEndSh, acceptPrefix, doneF, advSh;

  const int tid = threadIdx.x;
  const int wv = tid >> 6, lane = tid & 63;
  if (V > MAXV) return;

  for (int i = tid; i < MAXV / 32; i += 1024) { aliveb[i] = ~0u; touchb[i] = 0u; }
  if (tid == 0) {
    Psh = 0; winEndSh = (E < WSZ) ? E : WSZ;
    acceptPrefix = 0; doneF = 0; cqn = 0; allDirty = 0;
  }
  __syncthreads();
  if (tid < winEndSh) {
    unsigned pk = packed[tid];
    sv0[tid] = (unsigned short)(pk & 0x3FFFu);
    sv1[tid] = (unsigned short)((pk >> 14) & 0x3FFFu);
    sabs[tid] = tid;
    stat[tid] = ((pk >> 28) & 1u) ? 0 : 1;
    needR[tid] = 1; tentf[tid] = 0;
  } else {
    stat[tid] = 1; sabs[tid] = -(1 << 29); needR[tid] = 0;
  }
  __syncthreads();

  for (int round = 0; round < 30000; ++round) {
    // ---- A: build refresh queue ----
    if (tid == 0) rqn = 0;
    __syncthreads();
    if (stat[tid] == 0 && needR[tid]) { int q = atomicAdd(&rqn, 1); rque[q] = (unsigned short)tid; }
    __syncthreads();
    // ---- B: thread-per-candidate refresh ----
    for (int qi = tid; qi < rqn; qi += 1024) {
      int c = rque[qi];
      int v0 = sv0[c], v1 = sv1[c];
      bool a0 = (aliveb[v0 >> 5] >> (v0 & 31)) & 1;
      bool a1 = (aliveb[v1 >> 5] >> (v1 & 31)) & 1;
      if (!a0 || !a1) { stat[c] = 1; needR[c] = 0; continue; }
      int pcnt = 0, n0 = 0, n1 = 0;
      for (int d = 0; d < 16; ++d) {
        unsigned sd0 = summ[(size_t)v0 * 16 + d];
        unsigned sd1 = summ[(size_t)v1 * 16 + d];
        unsigned mi = sd0 & sd1;
        while (mi) {
          int b = __builtin_ctz(mi); mi &= mi - 1;
          int dw = d * 32 + b;
          pcnt += __popc(bs[(size_t)v0 * 512 + dw] & bs[(size_t)v1 * 512 + dw]);
        }
        unsigned m0 = sd0;
        while (m0) {
          int b = __builtin_ctz(m0); m0 &= m0 - 1;
          int dw = d * 32 + b;
          unsigned w = bs[(size_t)v0 * 512 + dw];
          while (w) {
            int bb = __builtin_ctz(w); w &= w - 1;
            if (n0 < LCAP) wl0[c * LCAP + n0] = (unsigned short)(dw * 32 + bb);
            n0++;
          }
        }
        unsigned m1 = sd1;
        while (m1) {
          int b = __builtin_ctz(m1); m1 &= m1 - 1;
          int dw = d * 32 + b;
          unsigned w = bs[(size_t)v1 * 512 + dw];
          while (w) {
            int bb = __builtin_ctz(w); w &= w - 1;
            if (n1 < LCAP) wl1[c * LCAP + n1] = (unsigned short)(dw * 32 + bb);
            n1++;
          }
        }
      }
      unsigned tf = (pcnt == 2) ? 1u : 0u;
      if (n0 > LCAP || n1 > LCAP) tf |= 2u;
      tentf[c] = (unsigned char)tf;
      n0c[c] = (unsigned char)(n0 < LCAP ? n0 : LCAP);
      n1c[c] = (unsigned char)(n1 < LCAP ? n1 : LCAP);
      needR[c] = 0;
    }
    asm volatile("s_waitcnt vmcnt(0)" ::: "memory");
    __syncthreads();
    // ---- C: inner LDS-only decision cascade ----
    for (int it = 0; it < 8; ++it) {
      for (int i = tid; i < MAXV; i += 1024) { Eres[i] = ~0u; V1res[i] = ~0u; }
      if (tid == 0) { minRes = 1 << 30; minU = 1 << 30; progress = 0; }
      __syncthreads();
      {
        unsigned char s = stat[tid];
        if (s == 0 || s == 2) {
          int r = sabs[tid] - Psh;
          atomicMin(&Eres[sv0[tid]], (unsigned)r);
          atomicMin(&Eres[sv1[tid]], (unsigned)r);
          atomicMin(&V1res[sv1[tid]], (unsigned)r);
          atomicMin(&minRes, r);
          if (s == 0) atomicMin(&minU, r);
        }
      }
      __syncthreads();
      if (stat[tid] == 0 && !needR[tid]) {
        int c = tid;
        int r = sabs[c] - Psh;
        int v0 = sv0[c], v1 = sv1[c];
        bool blocked = false;
        if (tentf[c] & 2) {
          blocked = (r != minRes);
        } else if (Eres[v0] < (unsigned)r || Eres[v1] < (unsigned)r) {
          blocked = true;
        } else {
          int n0 = n0c[c], n1 = n1c[c];
          for (int i = 0; i < n0 && !blocked; ++i) {
            int x = wl0[c * LCAP + i];
            if (V1res[x] < (unsigned)r) blocked = true;
          }
          for (int i = 0; i < n1 && !blocked; ++i) {
            int u = wl1[c * LCAP + i];
            if (V1res[u] < (unsigned)r || Eres[u] < (unsigned)r) blocked = true;
          }
        }
        if (!blocked) {
          progress = 1;
          if (tentf[c] & 1) {
            stat[c] = 2;
            int q = atomicAdd(&cqn, 1);
            cque[q] = (unsigned short)c;
            atomicOr(&touchb[v0 >> 5], 1u << (v0 & 31));
            atomicOr(&touchb[v1 >> 5], 1u << (v1 & 31));
            if (tentf[c] & 2) {
              allDirty = 1;
            } else {
              int n1 = n1c[c];
              for (int i = 0; i < n1; ++i) {
                int u = wl1[c * LCAP + i];
                atomicOr(&touchb[u >> 5], 1u << (u & 31));
              }
            }
          } else {
            stat[c] = 1;
          }
        }
      }
      __syncthreads();
      if (stat[tid] == 0) {
        if (allDirty) needR[tid] = 1;
        else {
          int v0 = sv0[tid], v1 = sv1[tid];
          if (((touchb[v0 >> 5] >> (v0 & 31)) & 1) ||
              ((touchb[v1 >> 5] >> (v1 & 31)) & 1)) needR[tid] = 1;
        }
      }
      __syncthreads();
      int prog = progress;
      for (int i = tid; i < MAXV / 32; i += 1024) touchb[i] = 0u;
      if (tid == 0) allDirty = 0;
      __syncthreads();
      if (!prog) break;
    }
    // ---- D: commit pending accepts (wave-cooperative, non-interfering) ----
    for (int qi = wv; qi < cqn; qi += 16) {
      int c = cque[qi];
      int v0 = sv0[c], v1 = sv1[c], abss = sabs[c];
      int d = lane & 15, q = lane >> 4;
      unsigned sd0 = summ[(size_t)v0 * 16 + d];
      unsigned sd1 = summ[(size_t)v1 * 16 + d];
      unsigned un = sd0 | sd1;
      unsigned m = un;
      while (m) {
        int b = __builtin_ctz(m); m &= m - 1;
        if ((b & 3) != q) continue;
        int dw = d * 32 + b;
        unsigned mw = bs[(size_t)v0 * 512 + dw] | bs[(size_t)v1 * 512 + dw];
        if (dw == (v0 >> 5)) mw &= ~(1u << (v0 & 31));
        if (dw == (v1 >> 5)) mw &= ~(1u << (v1 & 31));
        bs[(size_t)v0 * 512 + dw] = mw;
      }
      if (lane < 16) summ[(size_t)v0 * 16 + lane] = un;
      int w0d = v0 >> 5; unsigned b0m = 1u << (v0 & 31);
      int w1d = v1 >> 5; unsigned b1m = ~(1u << (v1 & 31));
      unsigned sb0 = 1u << (w0d & 31); int sw0 = w0d >> 5;
      m = sd1;
      while (m) {
        int b = __builtin_ctz(m); m &= m - 1;
        if ((b & 3) != q) continue;
        int dw = d * 32 + b;
        unsigned w = bs[(size_t)v1 * 512 + dw];
        while (w) {
          int bb = __builtin_ctz(w); w &= w - 1;
          int u = dw * 32 + bb;
          if (u == v0) continue;
          atomicAnd((unsigned*)&bs[(size_t)u * 512 + w1d], b1m);
          atomicOr((unsigned*)&bs[(size_t)u * 512 + w0d], b0m);
          atomicOr((unsigned*)&summ[(size_t)u * 16 + sw0], sb0);
        }
      }
      if (lane == 0) {
        atomicAnd(&aliveb[v1 >> 5], ~(1u << (v1 & 31)));
        aflag[abss] = 1;
        av0g[abss] = (unsigned short)v0;
        av1g[abss] = (unsigned short)v1;
        stat[c] = 3;
      }
    }
    asm volatile("s_waitcnt vmcnt(0)" ::: "memory");
    __syncthreads();
    if (tid == 0) cqn = 0;
    // ---- E: advance & slide ----
    if (tid == 0) minU = 1 << 30;
    __syncthreads();
    if (stat[tid] == 0) atomicMin(&minU, sabs[tid] - Psh);
    __syncthreads();
    if (tid == 0) advSh = (minU >= (1 << 29)) ? (winEndSh - Psh) : minU;
    __syncthreads();
    {
      int adv = advSh;
      int r = sabs[tid] - Psh;
      if (r >= 0 && r < adv && stat[tid] >= 2) atomicAdd(&acceptPrefix, 1);
    }
    __syncthreads();
    if (tid == 0) {
      int adv = advSh;
      int nP = Psh + adv, nEnd = nP + WSZ; if (nEnd > E) nEnd = E;
      advSh = winEndSh;          // pass old end
      Psh = nP; winEndSh = nEnd;
      if (acceptPrefix >= acceptTarget || nP >= E) doneF = 1;
    }
    __syncthreads();
    {
      int i = advSh + tid;       // advSh holds oldEnd
      if (i < winEndSh) {
        int c = i & (WSZ - 1);
        unsigned pk = packed[i];
        sv0[c] = (unsigned short)(pk & 0x3FFFu);
        sv1[c] = (unsigned short)((pk >> 14) & 0x3FFFu);
        sabs[c] = i;
        stat[c] = ((pk >> 28) & 1u) ? 0 : 1;
        needR[c] = 1; tentf[c] = 0;
      }
    }
    __syncthreads();
    if (doneF) break;
  }
}

// ---------------- compact accepts (slot order), cap at target --------------
__global__ void __launch_bounds__(1024)
k_compact(const unsigned char* __restrict__ aflag, const unsigned short* __restrict__ av0,
          const unsigned short* __restrict__ av1, int E, int target,
          int2* __restrict__ events, int* __restrict__ nev_out) {
  __shared__ int woff[16];
  __shared__ int runsh;
  int tid = threadIdx.x, wv = tid >> 6, lane = tid & 63;
  if (tid == 0) runsh = 0;
  __syncthreads();
  for (int base = 0; base < E; base += 1024) {
    int i = base + tid;
    int f = (i < E) ? aflag[i] : 0;
    u64 b = __ballot(f != 0);
    u64 below = (lane == 0) ? 0ull : (~0ull >> (64 - lane));
    int myr = __popcll(b & below);
    if (lane == 0) woff[wv] = __popcll(b);
    __syncthreads();
    if (tid == 0) {
      int s = runsh;
      for (int k = 0; k < 16; ++k) { int t = woff[k]; woff[k] = s; s += t; }
      runsh = s;
    }
    __syncthreads();
    if (f) {
      int pos = woff[wv] + myr;
      if (pos < target) events[pos] = make_int2((int)av0[i], (int)av1[i]);
    }
    __syncthreads();
  }
  if (tid == 0) nev_out[0] = runsh < target ? runsh : target;
}

// ---------------- reverse-replay: owner + weight per original vertex -------
__global__ void __launch_bounds__(256)
k_weights(const int2* __restrict__ events, const int* __restrict__ nev_p,
          int V, int* __restrict__ own, float* __restrict__ wgt) {
  __shared__ int O[MAXV];
  __shared__ unsigned short H[MAXV];
  __shared__ int2 evb[256];
  int tid = threadIdx.x;
  if (V > MAXV) return;
  for (int v = tid; v < V; v += blockDim.x) { O[v] = v; H[v] = 0; }
  int n = nev_p[0];
  __syncthreads();
  int nb = (n + 255) >> 8;
  for (int b = nb - 1; b >= 0; --b) {
    int bbase = b << 8;
    int cnt = n - bbase; if (cnt > 256) cnt = 256;
    if (tid < cnt) evb[tid] = events[bbase + tid];
    __syncthreads();
    if (tid == 0) {
      for (int k = cnt - 1; k >= 0; --k) {
        int2 ev = evb[k];
        int h = (int)H[ev.x] + 1;
        H[ev.x] = (unsigned short)h;
        H[ev.y] = (unsigned short)h;
        O[ev.y] = O[ev.x];
      }
    }
    __syncthreads();
  }
  for (int v = tid; v < V; v += blockDim.x) {
    own[v] = O[v];
    wgt[v] = ldexpf(1.0f, -(int)H[v]);
  }
}

// ---------------- output ---------------------------------------------------
__global__ void k_scatter(const float* __restrict__ img, const int* __restrict__ own,
                          const float* __restrict__ wgt, float* __restrict__ out, int V) {
  int v = blockIdx.x;
  if (v >= V) return;
  float w = wgt[v];
  int o = own[v];
  const float* src = img + (size_t)v * F_DIM;
  float* dst = out + (size_t)o * F_DIM;
  if (w == 1.0f) {
    for (int f = threadIdx.x; f < F_DIM; f += blockDim.x) dst[f] = src[f];
  } else {
    for (int f = threadIdx.x; f < F_DIM; f += blockDim.x) atomicAdd(&dst[f], w * src[f]);
  }
}

extern "C" void kernel_launch(void* const* d_in, const int* in_sizes, int n_in,
                              void* d_out, int out_size, void* d_ws, size_t ws_size,
                              hipStream_t stream) {
  const float* img  = (const float*)d_in[0];
  const int* edges  = (const int*)d_in[1];
  const float* vs   = (const float*)d_in[2];
  int V = in_sizes[2] / 2;
  int E = in_sizes[1] / 2;
  int P = 1; while (P < E) P <<= 1;

  char* wsp = (char*)d_ws;
  size_t off = 0;
  auto alloc = [&](size_t bytes) -> void* {
    void* p = (void*)(wsp + off);
    off = (off + bytes + 255) & ~(size_t)255;
    return p;
  };
  double* sqd          = (double*)alloc((size_t)V * 8);
  u64* keys            = (u64*)alloc((size_t)P * 8);
  unsigned char* elig  = (unsigned char*)alloc((size_t)E);
  unsigned* packed     = (unsigned*)alloc((size_t)E * 4);
  unsigned* summ       = (unsigned*)alloc((size_t)V * 16 * 4);
  unsigned char* aflag = (unsigned char*)alloc((size_t)E + 4);
  unsigned short* av0  = (unsigned short*)alloc((size_t)E * 2);
  unsigned short* av1  = (unsigned short*)alloc((size_t)E * 2);
  unsigned short* wl0  = (unsigned short*)alloc((size_t)WSZ * LCAP * 2);
  unsigned short* wl1  = (unsigned short*)alloc((size_t)WSZ * LCAP * 2);
  int2* events         = (int2*)alloc((size_t)(V / 2 + 64) * 8);
  int* nev             = (int*)alloc(256);
  int* own             = (int*)alloc((size_t)V * 4);
  float* wgt           = (float*)alloc((size_t)V * 4);

  unsigned* bs = (unsigned*)d_out;   // 9216 rows x 2048B == out buffer exactly
  int n4 = V * F_DIM;                // dwords in d_out
  int acceptTarget = V - V / 2;

  hipLaunchKernelGGL(k_sq, dim3(V), dim3(64), 0, stream, img, sqd, V);
  hipLaunchKernelGGL(k_prep, dim3((E + 255) / 256), dim3(256), 0, stream, vs, edges, E, elig);
  hipLaunchKernelGGL(k_keys, dim3((P + 255) / 256), dim3(256), 0, stream, sqd, edges, E, P, keys);
  hipLaunchKernelGGL(k_sort, dim3(1), dim3(1024), 0, stream, keys, P);
  hipLaunchKernelGGL(k_reorder, dim3((E + 255) / 256), dim3(256), 0, stream, keys, edges, elig, E, packed);
  hipLaunchKernelGGL(k_zero32, dim3((n4 + 255) / 256), dim3(256), 0, stream, bs, n4);
  int nsum = V * 16;
  hipLaunchKernelGGL(k_zero32, dim3((nsum + 255) / 256), dim3(256), 0, stream, summ, nsum);
  int nafl = (E + 7) / 4;
  hipLaunchKernelGGL(k_zero32, dim3((nafl + 255) / 256), dim3(256), 0, stream, (unsigned*)aflag, nafl);
  hipLaunchKernelGGL(k_bs_build, dim3((E + 255) / 256), dim3(256), 0, stream, edges, E, bs, summ);
  hipLaunchKernelGGL(k_pardec, dim3(1), dim3(1024), 0, stream,
                     E, V, acceptTarget, packed,
                     (volatile unsigned*)bs, (volatile unsigned*)summ,
                     aflag, av0, av1,
                     (volatile unsigned short*)wl0, (volatile unsigned short*)wl1);
  hipLaunchKernelGGL(k_compact, dim3(1), dim3(1024), 0, stream, aflag, av0, av1, E, acceptTarget, events, nev);
  hipLaunchKernelGGL(k_weights, dim3(1), dim3(256), 0, stream, events, nev, V, own, wgt);
  hipLaunchKernelGGL(k_zero32, dim3((n4 + 255) / 256), dim3(256), 0, stream, (unsigned*)d_out, n4);
  hipLaunchKernelGGL(k_scatter, dim3(V), dim3(256), 0, stream, img, own, wgt, (float*)d_out, V);
}

// Round 10
// 8584.678 us; speedup vs baseline: 1.2137x; 1.1667x over previous
//
#include <hip/hip_runtime.h>
#include <stdint.h>

#define F_DIM 512
#define CAP   64
#define MAXV  9216
#define CHK   16

typedef unsigned long long u64;

// ---------------- per-vertex squared norm (fp64 accumulate) ----------------
__global__ void k_sq(const float* __restrict__ img, double* __restrict__ sqd, int V) {
  int v = blockIdx.x;
  if (v >= V) return;
  const float* row = img + (size_t)v * F_DIM;
  double s = 0.0;
  for (int f = threadIdx.x; f < F_DIM; f += 64) {
    double x = (double)row[f];
    s += x * x;
  }
  for (int off = 32; off > 0; off >>= 1) s += __shfl_down(s, off);
  if (threadIdx.x == 0) sqd[v] = s;
}

// ---------------- zero degrees + edge eligibility (boundary test) ----------
__global__ void k_prep(const float* __restrict__ vs, const int* __restrict__ edges,
                       int V, int E, int* __restrict__ deg, unsigned char* __restrict__ elig) {
  int i = blockIdx.x * blockDim.x + threadIdx.x;
  if (i < V) deg[i] = 0;
  if (i < E) {
    int a = edges[i], b = edges[E + i];
    float ax = vs[2 * a], ay = vs[2 * a + 1];
    float bx = vs[2 * b], by = vs[2 * b + 1];
    const float eps = 1e-3f;
    const float hi = 1.0f - 1e-3f;
    bool ba = (ax < eps) || (ax > hi) || (ay < eps) || (ay > hi);
    bool bb = (bx < eps) || (bx > hi) || (by < eps) || (by > hi);
    elig[i] = (!ba && !bb) ? 1 : 0;
  }
}

// ---------------- build neighbor lists -------------------------------------
__global__ void k_lists(const int* __restrict__ edges, int E,
                        int* __restrict__ deg, unsigned short* __restrict__ nbr) {
  int e = blockIdx.x * blockDim.x + threadIdx.x;
  if (e >= E) return;
  int a = edges[e], b = edges[E + e];
  int ia = atomicAdd(&deg[a], 1);
  nbr[a * CAP + ia] = (unsigned short)b;
  int ib = atomicAdd(&deg[b], 1);
  nbr[b * CAP + ib] = (unsigned short)a;
}

// ---------------- sortable keys: prio(double) top bits | edge id -----------
__global__ void k_keys(const double* __restrict__ sqd, const int* __restrict__ edges,
                       int E, int P, u64* __restrict__ keys) {
  int e = blockIdx.x * blockDim.x + threadIdx.x;
  if (e >= P) return;
  if (e < E) {
    double prio = sqd[edges[e]] + sqd[edges[E + e]];
    u64 bits = (u64)__double_as_longlong(prio);
    keys[e] = (bits & ~0xFFFFull) | (u64)e;
  } else {
    keys[e] = ~0ull;
  }
}

// ---------------- single-block bitonic sort, LDS-staged --------------------
#define SCH 4096
__global__ void __launch_bounds__(1024)
k_sort(u64* __restrict__ keys, int n) {
  __shared__ u64 buf[SCH];
  int tid = threadIdx.x;
  int nt = blockDim.x;
  int ch = n < SCH ? n : SCH;
  for (int chunk = 0; chunk < n; chunk += ch) {
    for (int i = tid; i < ch; i += nt) buf[i] = keys[chunk + i];
    __syncthreads();
    for (int k = 2; k <= ch; k <<= 1) {
      for (int j = k >> 1; j > 0; j >>= 1) {
        for (int li = tid; li < ch; li += nt) {
          int lj = li ^ j;
          if (lj > li) {
            u64 x = buf[li], y = buf[lj];
            bool up = (((chunk + li) & k) == 0);
            if (up ? (x > y) : (x < y)) { buf[li] = y; buf[lj] = x; }
          }
        }
        __syncthreads();
      }
    }
    for (int i = tid; i < ch; i += nt) keys[chunk + i] = buf[i];
    __syncthreads();
  }
  for (int k = (ch << 1); k <= n; k <<= 1) {
    for (int j = k >> 1; j >= ch; j >>= 1) {
      for (int i = tid; i < n; i += nt) {
        int ixj = i ^ j;
        if (ixj > i) {
          u64 x = keys[i], y = keys[ixj];
          bool up = ((i & k) == 0);
          if (up ? (x > y) : (x < y)) { keys[i] = y; keys[ixj] = x; }
        }
      }
      __syncthreads();
    }
    for (int chunk = 0; chunk < n; chunk += ch) {
      for (int i = tid; i < ch; i += nt) buf[i] = keys[chunk + i];
      __syncthreads();
      for (int j = ch >> 1; j > 0; j >>= 1) {
        for (int li = tid; li < ch; li += nt) {
          int lj = li ^ j;
          if (lj > li) {
            u64 x = buf[li], y = buf[lj];
            bool up = (((chunk + li) & k) == 0);
            if (up ? (x > y) : (x < y)) { buf[li] = y; buf[lj] = x; }
          }
        }
        __syncthreads();
      }
      for (int i = tid; i < ch; i += nt) keys[chunk + i] = buf[i];
      __syncthreads();
    }
  }
}

// ---------------- gather sorted (v0,v1,elig) into one packed word ----------
__global__ void k_reorder(const u64* __restrict__ keys, const int* __restrict__ edges,
                          const unsigned char* __restrict__ elig, int E,
                          unsigned* __restrict__ packed) {
  int t = blockIdx.x * blockDim.x + threadIdx.x;
  if (t >= E) return;
  int eid = (int)(keys[t] & 0xFFFFull);
  unsigned v0 = (unsigned)edges[eid];
  unsigned v1 = (unsigned)edges[E + eid];
  unsigned el = (unsigned)elig[eid];
  packed[t] = v0 | (v1 << 14) | (el << 28);
}

// path-halving find on LDS union-find (benign races: parents always valid)
__device__ __forceinline__ int findroot(unsigned short* ren, int x) {
  while (true) {
    int p = ren[x];
    if (p == x) return x;
    int q = ren[p];
    if (q == p) return p;
    ren[x] = (unsigned short)q;
    x = q;
  }
}

// ---------------- chunked eval/commit decimation ---------------------------
// 16 waves evaluate the next 16 sorted candidates in parallel against the
// current lazy-row state (R5 substrate: raw rows + ren union-find + rln).
// Wave 0 then decides strictly in slot order; a result is invalidated only
// if an earlier same-chunk commit's {cv0,cv1} hits its endpoints or posted
// resolved-root arrays (the exact read-set). Conflicts slide the chunk.
__global__ void __launch_bounds__(1024, 1)
k_decimate(int E, int V, int target, const unsigned* __restrict__ packed,
           const int* __restrict__ deg_g, unsigned short* __restrict__ nbr,
           int2* __restrict__ events, int* __restrict__ nev_out) {
  __shared__ unsigned short ren[MAXV];
  __shared__ unsigned short rln[MAXV];
  __shared__ unsigned pkWin[1024];
  __shared__ unsigned short candIdx[1024];
  __shared__ unsigned short postA[CHK][64];
  __shared__ unsigned short postB[CHK][64];
  __shared__ unsigned short postP[CHK][64];
  __shared__ unsigned postMeta[CHK];
  __shared__ int wofs[16];
  __shared__ int candN, chunkBaseSh, doneSh;

  const int tid = threadIdx.x;
  const int wv = tid >> 6, lane = tid & 63;
  const u64 lanebit = 1ull << lane;
  const u64 below = lanebit - 1;
  if (V > MAXV) return;

  for (int v = tid; v < V; v += 1024) {
    ren[v] = (unsigned short)v;
    rln[v] = (unsigned short)deg_g[v];
  }
  if (tid == 0) doneSh = 0;
  __syncthreads();

  int count = V, nev = 0;   // authoritative in wave 0 (uniform there)

  for (int winBase = 0; winBase < E; winBase += 1024) {
    // ---- window build: prefilter + compact candidate list (slot order) ----
    int gi = winBase + tid;
    unsigned pk = (gi < E) ? packed[gi] : 0u;
    pkWin[tid] = pk;
    int bv0 = (int)(pk & 0x3FFFu), bv1 = (int)((pk >> 14) & 0x3FFFu);
    bool ok = (gi < E) && ((pk >> 28) & 1u) && rln[bv0] > 0 && rln[bv1] > 0;
    u64 bal = __ballot(ok);
    int myr = __popcll(bal & below);
    if (lane == 0) wofs[wv] = __popcll(bal);
    __syncthreads();
    if (tid == 0) {
      int s = 0;
      for (int k = 0; k < 16; ++k) { int t = wofs[k]; wofs[k] = s; s += t; }
      candN = s; chunkBaseSh = 0;
    }
    __syncthreads();
    if (ok) candIdx[wofs[wv] + myr] = (unsigned short)tid;
    __syncthreads();

    while (true) {
      int cb = chunkBaseSh;
      if (doneSh || cb >= candN) break;
      // ================= EVAL phase (all 16 waves) ==================
      int myslot = cb + wv;
      if (myslot < candN) {
        unsigned mpk = pkWin[candIdx[myslot]];
        int v0 = (int)(mpk & 0x3FFFu), v1 = (int)((mpk >> 14) & 0x3FFFu);
        int L0 = rln[v0], L1 = rln[v1];
        if (L0 == 0 || L1 == 0) {
          postA[wv][lane] = 0xFFFF; postB[wv][lane] = 0xFFFF;
          if (lane == 0) postMeta[wv] = 1u;        // dead -> reject (final)
        } else {
          unsigned rawA = (lane < L0) ? (unsigned)nbr[v0 * CAP + lane] : 0xFFFFu;
          unsigned rawB = (lane < L1) ? (unsigned)nbr[v1 * CAP + lane] : 0xFFFFu;
          unsigned rA = (lane < L0) ? (unsigned)findroot(ren, (int)rawA) : 0xFFFFu;
          unsigned rB = (lane < L1) ? (unsigned)findroot(ren, (int)rawB) : 0xFFFFu;
          postA[wv][lane] = (unsigned short)rA;
          postB[wv][lane] = (unsigned short)rB;
          bool vA = lane < L0 && rA != (unsigned)v0 && rA != (unsigned)v1;
          bool vB = lane < L1 && rB != (unsigned)v0 && rB != (unsigned)v1;
          bool cA = vA, cB = vB, hA = false, hB = false;
          int mx = L0 > L1 ? L0 : L1;
          for (int k = 0; k < mx; ++k) {
            unsigned ak = (unsigned)__shfl((int)rA, k);
            unsigned bk = (unsigned)__shfl((int)rB, k);
            bool akV = (k < L0) && ak != (unsigned)v0 && ak != (unsigned)v1;
            bool bkV = (k < L1) && bk != (unsigned)v0 && bk != (unsigned)v1;
            if (akV) { if (k < lane && ak == rA) cA = false; if (ak == rB) hB = true; }
            if (bkV) { if (k < lane && bk == rB) cB = false; if (bk == rA) hA = true; }
          }
          int nshared = __popcll(__ballot(vA && cA && hA));
          unsigned tent = (nshared == 2) ? 1u : 0u;
          unsigned type, nd;
          if (L0 + L1 <= CAP) {
            type = 0; nd = (unsigned)(L0 + L1);
            if (lane < L1) postP[wv][lane] = (unsigned short)rB;   // resolved append
          } else {
            bool pa = vA && cA;
            bool pb = vB && cB && !hB;
            u64 ma = __ballot(pa), mb = __ballot(pb);
            int na = __popcll(ma);
            int tot = na + __popcll(mb); if (tot > CAP) tot = CAP;
            if (pa) postP[wv][__popcll(ma & below)] = (unsigned short)rA;
            if (pb) { int pos = na + __popcll(mb & below); if (pos < CAP) postP[wv][pos] = (unsigned short)rB; }
            type = 1; nd = (unsigned)tot;
          }
          if (lane == 0)
            postMeta[wv] = 3u | (tent << 2) | (type << 3) | (nd << 4) |
                           ((unsigned)L0 << 11) | ((unsigned)L1 << 18);
        }
      }
      __syncthreads();
      // ================= SERIAL phase (wave 0, slot order) ==========
      if (wv == 0) {
        unsigned ra[CHK], rb[CHK], mt[CHK], pkv[CHK];
#pragma unroll
        for (int j = 0; j < CHK; ++j) {
          int s = cb + j;
          if (s < candN) {
            pkv[j] = pkWin[candIdx[s]];
            ra[j] = postA[j][lane]; rb[j] = postB[j][lane];
            mt[j] = postMeta[j];
          } else { mt[j] = 0u; ra[j] = 0xFFFFu; rb[j] = 0xFFFFu; pkv[j] = 0x0FFFFFFFu; }
        }
        unsigned cl[CHK];
        int ncommit = 0, consumed = 0;
        bool halt = false, done = false;
#pragma unroll
        for (int j = 0; j < CHK; ++j) {
          if (halt) continue;
          int s = cb + j;
          if (s >= candN) { consumed++; continue; }
          unsigned m = mt[j];
          if ((m & 3u) == 1u) { consumed++; continue; }   // dead: final reject
          unsigned v0 = pkv[j] & 0x3FFFu, v1 = (pkv[j] >> 14) & 0x3FFFu;
          // staleness vs earlier same-chunk commits
          bool st = false;
#pragma unroll
          for (int c = 0; c < CHK; ++c) if (c < ncommit) {
            unsigned c0 = cl[c] & 0xFFFFu, c1 = cl[c] >> 16;
            st = st || (v0 == c0) || (v0 == c1) || (v1 == c0) || (v1 == c1);
            st = st || (ra[j] == c0) || (ra[j] == c1) || (rb[j] == c0) || (rb[j] == c1);
          }
          if (__ballot(st) != 0ull) { halt = true; continue; }   // DEFER: slide chunk
          if (((m >> 2) & 1u) == 0u) { consumed++; continue; }   // reject
          // ---- COMMIT (lazy merge v1 -> v0) ----
          unsigned type = (m >> 3) & 1u;
          unsigned nd = (m >> 4) & 0x7Fu;
          unsigned L0 = (m >> 11) & 0x7Fu;
          unsigned L1 = (m >> 18) & 0x7Fu;
          unsigned pay = postP[j][lane];
          if (type == 0u) {
            unsigned ndc = nd > CAP ? (unsigned)CAP : nd;
            if (lane < (int)L1) nbr[v0 * CAP + L0 + lane] = (unsigned short)pay;
            if (lane == 0) rln[v0] = (unsigned short)ndc;
          } else {
            if (lane < (int)nd) nbr[v0 * CAP + lane] = (unsigned short)pay;
            if (lane == 0) rln[v0] = (unsigned short)nd;
          }
          if (lane == 0) {
            rln[v1] = 0;
            ren[v1] = (unsigned short)v0;
            events[nev] = make_int2((int)v0, (int)v1);
          }
#pragma unroll
          for (int c = 0; c < CHK; ++c) if (c == ncommit) cl[c] = v0 | (v1 << 16);
          ncommit++;
          nev++; count--; consumed++;
          if (count <= target) { done = true; halt = true; }
        }
        if (lane == 0) {
          chunkBaseSh = cb + consumed;
          if (done) doneSh = 1;
        }
      }
      __syncthreads();   // drains wave0 stores; publishes chunkBaseSh/doneSh
    }
    __syncthreads();
    if (doneSh) break;
  }
  if (tid == 0) nev_out[0] = nev;
}

// ---------------- reverse-replay: owner + weight per original vertex -------
__global__ void __launch_bounds__(256)
k_weights(const int2* __restrict__ events, const int* __restrict__ nev_p,
          int V, int* __restrict__ own, float* __restrict__ wgt) {
  __shared__ int O[MAXV];
  __shared__ unsigned short H[MAXV];
  __shared__ int2 evb[256];
  int tid = threadIdx.x;
  if (V > MAXV) return;
  for (int v = tid; v < V; v += blockDim.x) { O[v] = v; H[v] = 0; }
  int n = nev_p[0];
  __syncthreads();
  int nb = (n + 255) >> 8;
  for (int b = nb - 1; b >= 0; --b) {
    int bbase = b << 8;
    int cnt = n - bbase; if (cnt > 256) cnt = 256;
    if (tid < cnt) evb[tid] = events[bbase + tid];
    __syncthreads();
    if (tid == 0) {
      for (int k = cnt - 1; k >= 0; --k) {
        int2 ev = evb[k];
        int h = (int)H[ev.x] + 1;
        H[ev.x] = (unsigned short)h;
        H[ev.y] = (unsigned short)h;
        O[ev.y] = O[ev.x];
      }
    }
    __syncthreads();
  }
  for (int v = tid; v < V; v += blockDim.x) {
    own[v] = O[v];
    wgt[v] = ldexpf(1.0f, -(int)H[v]);
  }
}

// ---------------- output ---------------------------------------------------
__global__ void k_zero(float4* __restrict__ out, int n4) {
  int i = blockIdx.x * blockDim.x + threadIdx.x;
  if (i < n4) out[i] = make_float4(0.f, 0.f, 0.f, 0.f);
}

__global__ void k_scatter(const float* __restrict__ img, const int* __restrict__ own,
                          const float* __restrict__ wgt, float* __restrict__ out, int V) {
  int v = blockIdx.x;
  if (v >= V) return;
  float w = wgt[v];
  int o = own[v];
  const float* src = img + (size_t)v * F_DIM;
  float* dst = out + (size_t)o * F_DIM;
  if (w == 1.0f) {
    for (int f = threadIdx.x; f < F_DIM; f += blockDim.x) dst[f] = src[f];
  } else {
    for (int f = threadIdx.x; f < F_DIM; f += blockDim.x) atomicAdd(&dst[f], w * src[f]);
  }
}

extern "C" void kernel_launch(void* const* d_in, const int* in_sizes, int n_in,
                              void* d_out, int out_size, void* d_ws, size_t ws_size,
                              hipStream_t stream) {
  const float* img  = (const float*)d_in[0];
  const int* edges  = (const int*)d_in[1];
  const float* vs   = (const float*)d_in[2];
  int V = in_sizes[2] / 2;
  int E = in_sizes[1] / 2;
  int P = 1; while (P < E) P <<= 1;

  char* wsp = (char*)d_ws;
  size_t off = 0;
  auto alloc = [&](size_t bytes) -> void* {
    void* p = (void*)(wsp + off);
    off = (off + bytes + 255) & ~(size_t)255;
    return p;
  };
  double* sqd          = (double*)alloc((size_t)V * 8);
  u64* keys            = (u64*)alloc((size_t)P * 8);
  int* deg             = (int*)alloc((size_t)V * 4);
  unsigned short* nbr  = (unsigned short*)alloc((size_t)V * CAP * 2 + 256);
  unsigned char* elig  = (unsigned char*)alloc((size_t)E);
  unsigned* packed     = (unsigned*)alloc((size_t)E * 4);
  int2* events         = (int2*)alloc((size_t)(V / 2 + 64) * 8);
  int* nev             = (int*)alloc(256);
  int* own             = (int*)alloc((size_t)V * 4);
  float* wgt           = (float*)alloc((size_t)V * 4);

  hipLaunchKernelGGL(k_sq, dim3(V), dim3(64), 0, stream, img, sqd, V);
  int mx = V > E ? V : E;
  hipLaunchKernelGGL(k_prep, dim3((mx + 255) / 256), dim3(256), 0, stream, vs, edges, V, E, deg, elig);
  hipLaunchKernelGGL(k_lists, dim3((E + 255) / 256), dim3(256), 0, stream, edges, E, deg, nbr);
  hipLaunchKernelGGL(k_keys, dim3((P + 255) / 256), dim3(256), 0, stream, sqd, edges, E, P, keys);
  hipLaunchKernelGGL(k_sort, dim3(1), dim3(1024), 0, stream, keys, P);
  hipLaunchKernelGGL(k_reorder, dim3((E + 255) / 256), dim3(256), 0, stream, keys, edges, elig, E, packed);
  hipLaunchKernelGGL(k_decimate, dim3(1), dim3(1024), 0, stream,
                     E, V, V / 2, packed, deg, nbr, events, nev);
  hipLaunchKernelGGL(k_weights, dim3(1), dim3(256), 0, stream, events, nev, V, own, wgt);
  int n4 = (V * F_DIM) / 4;
  hipLaunchKernelGGL(k_zero, dim3((n4 + 255) / 256), dim3(256), 0, stream, (float4*)d_out, n4);
  hipLaunchKernelGGL(k_scatter, dim3(V), dim3(256), 0, stream, img, own, wgt, (float*)d_out, V);
}

// Round 11
// 5980.243 us; speedup vs baseline: 1.7423x; 1.4355x over previous
//
#include <hip/hip_runtime.h>
#include <stdint.h>

#define F_DIM 512
#define CAP   64
#define MAXV  9216
#define GD    16

typedef unsigned long long u64;

// ---------------- per-vertex squared norm (fp64 accumulate) ----------------
__global__ void k_sq(const float* __restrict__ img, double* __restrict__ sqd, int V) {
  int v = blockIdx.x;
  if (v >= V) return;
  const float* row = img + (size_t)v * F_DIM;
  double s = 0.0;
  for (int f = threadIdx.x; f < F_DIM; f += 64) {
    double x = (double)row[f];
    s += x * x;
  }
  for (int off = 32; off > 0; off >>= 1) s += __shfl_down(s, off);
  if (threadIdx.x == 0) sqd[v] = s;
}

// ---------------- zero degrees + edge eligibility (boundary test) ----------
__global__ void k_prep(const float* __restrict__ vs, const int* __restrict__ edges,
                       int V, int E, int* __restrict__ deg, unsigned char* __restrict__ elig) {
  int i = blockIdx.x * blockDim.x + threadIdx.x;
  if (i < V) deg[i] = 0;
  if (i < E) {
    int a = edges[i], b = edges[E + i];
    float ax = vs[2 * a], ay = vs[2 * a + 1];
    float bx = vs[2 * b], by = vs[2 * b + 1];
    const float eps = 1e-3f;
    const float hi = 1.0f - 1e-3f;
    bool ba = (ax < eps) || (ax > hi) || (ay < eps) || (ay > hi);
    bool bb = (bx < eps) || (bx > hi) || (by < eps) || (by > hi);
    elig[i] = (!ba && !bb) ? 1 : 0;
  }
}

// ---------------- build neighbor lists -------------------------------------
__global__ void k_lists(const int* __restrict__ edges, int E,
                        int* __restrict__ deg, unsigned short* __restrict__ nbr) {
  int e = blockIdx.x * blockDim.x + threadIdx.x;
  if (e >= E) return;
  int a = edges[e], b = edges[E + e];
  int ia = atomicAdd(&deg[a], 1);
  nbr[a * CAP + ia] = (unsigned short)b;
  int ib = atomicAdd(&deg[b], 1);
  nbr[b * CAP + ib] = (unsigned short)a;
}

// ---------------- sortable keys: prio(double) top bits | edge id -----------
__global__ void k_keys(const double* __restrict__ sqd, const int* __restrict__ edges,
                       int E, int P, u64* __restrict__ keys) {
  int e = blockIdx.x * blockDim.x + threadIdx.x;
  if (e >= P) return;
  if (e < E) {
    double prio = sqd[edges[e]] + sqd[edges[E + e]];
    u64 bits = (u64)__double_as_longlong(prio);  // prio > 0 -> bits monotone
    keys[e] = (bits & ~0xFFFFull) | (u64)e;
  } else {
    keys[e] = ~0ull;
  }
}

// ---------------- single-block bitonic sort, LDS-staged --------------------
#define SCH 4096
__global__ void __launch_bounds__(1024)
k_sort(u64* __restrict__ keys, int n) {
  __shared__ u64 buf[SCH];
  int tid = threadIdx.x;
  int nt = blockDim.x;
  int ch = n < SCH ? n : SCH;
  for (int chunk = 0; chunk < n; chunk += ch) {
    for (int i = tid; i < ch; i += nt) buf[i] = keys[chunk + i];
    __syncthreads();
    for (int k = 2; k <= ch; k <<= 1) {
      for (int j = k >> 1; j > 0; j >>= 1) {
        for (int li = tid; li < ch; li += nt) {
          int lj = li ^ j;
          if (lj > li) {
            u64 x = buf[li], y = buf[lj];
            bool up = (((chunk + li) & k) == 0);
            if (up ? (x > y) : (x < y)) { buf[li] = y; buf[lj] = x; }
          }
        }
        __syncthreads();
      }
    }
    for (int i = tid; i < ch; i += nt) keys[chunk + i] = buf[i];
    __syncthreads();
  }
  for (int k = (ch << 1); k <= n; k <<= 1) {
    for (int j = k >> 1; j >= ch; j >>= 1) {
      for (int i = tid; i < n; i += nt) {
        int ixj = i ^ j;
        if (ixj > i) {
          u64 x = keys[i], y = keys[ixj];
          bool up = ((i & k) == 0);
          if (up ? (x > y) : (x < y)) { keys[i] = y; keys[ixj] = x; }
        }
      }
      __syncthreads();
    }
    for (int chunk = 0; chunk < n; chunk += ch) {
      for (int i = tid; i < ch; i += nt) buf[i] = keys[chunk + i];
      __syncthreads();
      for (int j = ch >> 1; j > 0; j >>= 1) {
        for (int li = tid; li < ch; li += nt) {
          int lj = li ^ j;
          if (lj > li) {
            u64 x = buf[li], y = buf[lj];
            bool up = (((chunk + li) & k) == 0);
            if (up ? (x > y) : (x < y)) { buf[li] = y; buf[lj] = x; }
          }
        }
        __syncthreads();
      }
      for (int i = tid; i < ch; i += nt) keys[chunk + i] = buf[i];
      __syncthreads();
    }
  }
}

// ---------------- gather sorted (v0,v1,elig) into one packed word ----------
__global__ void k_reorder(const u64* __restrict__ keys, const int* __restrict__ edges,
                          const unsigned char* __restrict__ elig, int E,
                          unsigned* __restrict__ packed) {
  int t = blockIdx.x * blockDim.x + threadIdx.x;
  if (t >= E) return;
  int eid = (int)(keys[t] & 0xFFFFull);
  unsigned v0 = (unsigned)edges[eid];
  unsigned v1 = (unsigned)edges[E + eid];
  unsigned el = (unsigned)elig[eid];
  packed[t] = v0 | (v1 << 14) | (el << 28);
}

// path-halving find on LDS union-find
__device__ __forceinline__ int findroot(unsigned short* ren, int x) {
  while (true) {
    int p = ren[x];
    if (p == x) return x;
    int q = ren[p];
    if (q == p) return p;
    ren[x] = (unsigned short)q;   // halving (benign race; roots invariant)
    x = q;
  }
}

// ---------------- sequential greedy decimation (single wave) ---------------
// Lazy-merge design (R5): rows are raw (may contain stale ids / duplicates);
// ren[] union-find resolves to live roots at read time; rln[] is exact raw
// length. Merge = append RESOLVED roots of raw(v1) to raw(v0) + ren[v1]=v0.
// Membership via versioned mark arrays with PLAIN writes (any surviving lane
// is a valid canonical representative; decisions depend only on sets).
__global__ void __launch_bounds__(64, 1)
k_decimate(int E, int V, int target, const unsigned* __restrict__ packed,
           const int* __restrict__ deg_g, unsigned short* __restrict__ nbr,
           int2* __restrict__ events, int* __restrict__ nev_out) {
  __shared__ unsigned short ren[MAXV];
  __shared__ unsigned short rln[MAXV];
  __shared__ unsigned markA[MAXV];
  __shared__ unsigned markB[MAXV];
  const int lane = threadIdx.x;
  if (V > MAXV) return;
  for (int v = lane; v < V; v += 64) {
    ren[v] = (unsigned short)v;
    rln[v] = (unsigned short)deg_g[v];
    markA[v] = 0u;
    markB[v] = 0u;
  }
  __syncthreads();

  int count = V, nev = 0;
  unsigned ctr = 0;
  bool stop = false;
  const u64 lanebit = 1ull << lane;
  const u64 below = lanebit - 1;

  for (int base = 0; base < E && !stop; base += 64) {
    int t = base + lane;
    unsigned pk = (t < E) ? packed[t] : 0u;
    int mv0 = (int)(pk & 0x3FFFu);
    int mv1 = (int)((pk >> 14) & 0x3FFFu);
    bool cand = (t < E) && ((pk >> 28) & 1u) &&
                (ren[mv0] == (unsigned short)mv0) &&
                (ren[mv1] == (unsigned short)mv1);
    u64 cm = __ballot(cand);

    while (cm != 0 && !stop) {
      // ---- pick up to GD candidates (static indices only) ----
      int ids[GD];
#pragma unroll
      for (int g = 0; g < GD; ++g) {
        if (cm) { ids[g] = __builtin_ctzll(cm); cm &= cm - 1; }
        else ids[g] = -1;
      }
      // drain prior appends, then gather all group rows (coalesced 128B each)
      asm volatile("s_waitcnt vmcnt(0)" ::: "memory");
      __builtin_amdgcn_sched_barrier(0);
      int gcv0[GD], gcv1[GD];
      unsigned ga[GD], gb[GD];
#pragma unroll
      for (int g = 0; g < GD; ++g) {
        if (ids[g] >= 0) {
          unsigned pkc = __builtin_amdgcn_readlane(pk, ids[g]);
          gcv0[g] = (int)(pkc & 0x3FFFu);
          gcv1[g] = (int)((pkc >> 14) & 0x3FFFu);
          ga[g] = (unsigned)nbr[gcv0[g] * CAP + lane];
          gb[g] = (unsigned)nbr[gcv1[g] * CAP + lane];
        } else { gcv0[g] = -1; gcv1[g] = -1; ga[g] = 0; gb[g] = 0; }
      }
      int app[GD];
#pragma unroll
      for (int g = 0; g < GD; ++g) app[g] = -1;

#pragma unroll
      for (int g = 0; g < GD; ++g) {
        if (ids[g] < 0 || stop) continue;
        int cv0 = gcv0[g], cv1 = gcv1[g];
        // aliveness (current LDS state)
        if (ren[cv0] != (unsigned short)cv0 || ren[cv1] != (unsigned short)cv1) continue;
        // staleness: only in-group accepted commits modify rows (row of app[j])
        bool stale = false;
#pragma unroll
        for (int j = 0; j < GD; ++j)
          if (j < g) stale = stale || (app[j] == cv0) || (app[j] == cv1);
        if (stale) {
          asm volatile("s_waitcnt vmcnt(0)" ::: "memory");
          __builtin_amdgcn_sched_barrier(0);
          ga[g] = (unsigned)nbr[cv0 * CAP + lane];
          gb[g] = (unsigned)nbr[cv1 * CAP + lane];
        }
        int L0 = rln[cv0], L1 = rln[cv1];
        unsigned rawA = ga[g], rawB = gb[g];

        // resolve raw entries to live roots
        int rA = 0x7FFF, rB = 0x7FFF;
        if (lane < L0) rA = findroot(ren, (int)rawA);
        if (lane < L1) rB = findroot(ren, (int)rawB);

        // versioned marks: dedup (canonical = surviving lane) + membership
        ctr++;
        unsigned enc = (ctr << 6) + (unsigned)lane;
        bool wA = (lane < L0) && (rA != cv0);   // eff(v0) excludes self
        bool wB = (lane < L1) && (rB != cv1);   // eff(v1) excludes self
        if (wA) markA[rA] = enc;                // plain write: one lane survives
        if (wB) markB[rB] = enc;
        asm volatile("s_waitcnt lgkmcnt(0)" ::: "memory");
        __builtin_amdgcn_sched_barrier(0);
        bool canonA = wA && (markA[rA] == enc);
        bool canonB = wB && (markB[rB] == enc);
        bool sh = canonA && ((markB[rA] >> 6) == ctr);   // rA in eff(v1)
        if (__popcll(__ballot(sh)) != 2) continue;

        // ---- commit merge cv1 -> cv0 ----
        if (L0 + L1 <= CAP) {
          // append resolved roots of raw(v1); dedup deferred to future reads
          if (lane < L1) nbr[cv0 * CAP + L0 + lane] = (unsigned short)rB;
          if (lane == 0) rln[cv0] = (unsigned short)(L0 + L1);
        } else {
          // compaction: write resolved deduped (effA ∪ effB) \ {cv0, cv1}
          bool pa = canonA && (rA != cv1);
          bool pb = canonB && (rB != cv0) && ((markA[rB] >> 6) != ctr);
          u64 ma = __ballot(pa);
          u64 mb = __ballot(pb);
          int na = __popcll(ma);
          int tot = na + __popcll(mb);
          if (tot > CAP) tot = CAP;
          if (pa) nbr[cv0 * CAP + __popcll(ma & below)] = (unsigned short)rA;
          if (pb) {
            int pos = na + __popcll(mb & below);
            if (pos < CAP) nbr[cv0 * CAP + pos] = (unsigned short)rB;
          }
          if (lane == 0) rln[cv0] = (unsigned short)tot;
        }
        if (lane == 0) {
          ren[cv1] = (unsigned short)cv0;
          events[nev] = make_int2(cv0, cv1);
        }
        asm volatile("s_waitcnt lgkmcnt(0)" ::: "memory");
        __builtin_amdgcn_sched_barrier(0);
        app[g] = cv0;
        nev++;
        count--;
        if (count <= target) stop = true;
      }
    }
  }
  if (lane == 0) nev_out[0] = nev;
}

// ---------------- reverse-replay: owner + weight per original vertex -------
__global__ void __launch_bounds__(256)
k_weights(const int2* __restrict__ events, const int* __restrict__ nev_p,
          int V, int* __restrict__ own, float* __restrict__ wgt) {
  __shared__ int O[MAXV];
  __shared__ unsigned short H[MAXV];
  __shared__ int2 evb[256];
  int tid = threadIdx.x;
  if (V > MAXV) return;
  for (int v = tid; v < V; v += blockDim.x) { O[v] = v; H[v] = 0; }
  int n = nev_p[0];
  __syncthreads();
  int nb = (n + 255) >> 8;
  for (int b = nb - 1; b >= 0; --b) {
    int bbase = b << 8;
    int cnt = n - bbase; if (cnt > 256) cnt = 256;
    if (tid < cnt) evb[tid] = events[bbase + tid];
    __syncthreads();
    if (tid == 0) {
      for (int k = cnt - 1; k >= 0; --k) {
        int2 ev = evb[k];
        int h = (int)H[ev.x] + 1;
        H[ev.x] = (unsigned short)h;
        H[ev.y] = (unsigned short)h;
        O[ev.y] = O[ev.x];
      }
    }
    __syncthreads();
  }
  for (int v = tid; v < V; v += blockDim.x) {
    own[v] = O[v];
    wgt[v] = ldexpf(1.0f, -(int)H[v]);
  }
}

// ---------------- output ---------------------------------------------------
__global__ void k_zero(float4* __restrict__ out, int n4) {
  int i = blockIdx.x * blockDim.x + threadIdx.x;
  if (i < n4) out[i] = make_float4(0.f, 0.f, 0.f, 0.f);
}

__global__ void k_scatter(const float* __restrict__ img, const int* __restrict__ own,
                          const float* __restrict__ wgt, float* __restrict__ out, int V) {
  int v = blockIdx.x;
  if (v >= V) return;
  float w = wgt[v];
  int o = own[v];
  const float* src = img + (size_t)v * F_DIM;
  float* dst = out + (size_t)o * F_DIM;
  if (w == 1.0f) {
    for (int f = threadIdx.x; f < F_DIM; f += blockDim.x) dst[f] = src[f];
  } else {
    for (int f = threadIdx.x; f < F_DIM; f += blockDim.x) atomicAdd(&dst[f], w * src[f]);
  }
}

extern "C" void kernel_launch(void* const* d_in, const int* in_sizes, int n_in,
                              void* d_out, int out_size, void* d_ws, size_t ws_size,
                              hipStream_t stream) {
  const float* img  = (const float*)d_in[0];
  const int* edges  = (const int*)d_in[1];
  const float* vs   = (const float*)d_in[2];
  int V = in_sizes[2] / 2;
  int E = in_sizes[1] / 2;
  int P = 1; while (P < E) P <<= 1;

  char* wsp = (char*)d_ws;
  size_t off = 0;
  auto alloc = [&](size_t bytes) -> void* {
    void* p = (void*)(wsp + off);
    off = (off + bytes + 255) & ~(size_t)255;
    return p;
  };
  double* sqd          = (double*)alloc((size_t)V * 8);
  u64* keys            = (u64*)alloc((size_t)P * 8);
  int* deg             = (int*)alloc((size_t)V * 4);
  unsigned short* nbr  = (unsigned short*)alloc((size_t)V * CAP * 2 + 256);
  unsigned char* elig  = (unsigned char*)alloc((size_t)E);
  unsigned* packed     = (unsigned*)alloc((size_t)E * 4);
  int2* events         = (int2*)alloc((size_t)(V / 2 + 64) * 8);
  int* nev             = (int*)alloc(256);
  int* own             = (int*)alloc((size_t)V * 4);
  float* wgt           = (float*)alloc((size_t)V * 4);

  hipLaunchKernelGGL(k_sq, dim3(V), dim3(64), 0, stream, img, sqd, V);
  int mx = V > E ? V : E;
  hipLaunchKernelGGL(k_prep, dim3((mx + 255) / 256), dim3(256), 0, stream, vs, edges, V, E, deg, elig);
  hipLaunchKernelGGL(k_lists, dim3((E + 255) / 256), dim3(256), 0, stream, edges, E, deg, nbr);
  hipLaunchKernelGGL(k_keys, dim3((P + 255) / 256), dim3(256), 0, stream, sqd, edges, E, P, keys);
  hipLaunchKernelGGL(k_sort, dim3(1), dim3(1024), 0, stream, keys, P);
  hipLaunchKernelGGL(k_reorder, dim3((E + 255) / 256), dim3(256), 0, stream, keys, edges, elig, E, packed);
  hipLaunchKernelGGL(k_decimate, dim3(1), dim3(64), 0, stream,
                     E, V, V / 2, packed, deg, nbr, events, nev);
  hipLaunchKernelGGL(k_weights, dim3(1), dim3(256), 0, stream, events, nev, V, own, wgt);
  int n4 = (V * F_DIM) / 4;
  hipLaunchKernelGGL(k_zero, dim3((n4 + 255) / 256), dim3(256), 0, stream, (float4*)d_out, n4);
  hipLaunchKernelGGL(k_scatter, dim3(V), dim3(256), 0, stream, img, own, wgt, (float*)d_out, V);
}

// Round 12
// 5009.212 us; speedup vs baseline: 2.0800x; 1.1938x over previous
//
#include <hip/hip_runtime.h>
#include <stdint.h>

#define F_DIM 512
#define CAP   64
#define MAXV  9216
#define GP    4     // pairs per prefetch group (8 candidates)

typedef unsigned long long u64;

// ---------------- per-vertex squared norm (fp64 accumulate) ----------------
__global__ void k_sq(const float* __restrict__ img, double* __restrict__ sqd, int V) {
  int v = blockIdx.x;
  if (v >= V) return;
  const float* row = img + (size_t)v * F_DIM;
  double s = 0.0;
  for (int f = threadIdx.x; f < F_DIM; f += 64) {
    double x = (double)row[f];
    s += x * x;
  }
  for (int off = 32; off > 0; off >>= 1) s += __shfl_down(s, off);
  if (threadIdx.x == 0) sqd[v] = s;
}

// ---------------- zero degrees + edge eligibility (boundary test) ----------
__global__ void k_prep(const float* __restrict__ vs, const int* __restrict__ edges,
                       int V, int E, int* __restrict__ deg, unsigned char* __restrict__ elig) {
  int i = blockIdx.x * blockDim.x + threadIdx.x;
  if (i < V) deg[i] = 0;
  if (i < E) {
    int a = edges[i], b = edges[E + i];
    float ax = vs[2 * a], ay = vs[2 * a + 1];
    float bx = vs[2 * b], by = vs[2 * b + 1];
    const float eps = 1e-3f;
    const float hi = 1.0f - 1e-3f;
    bool ba = (ax < eps) || (ax > hi) || (ay < eps) || (ay > hi);
    bool bb = (bx < eps) || (bx > hi) || (by < eps) || (by > hi);
    elig[i] = (!ba && !bb) ? 1 : 0;
  }
}

// ---------------- build neighbor lists -------------------------------------
__global__ void k_lists(const int* __restrict__ edges, int E,
                        int* __restrict__ deg, unsigned short* __restrict__ nbr) {
  int e = blockIdx.x * blockDim.x + threadIdx.x;
  if (e >= E) return;
  int a = edges[e], b = edges[E + e];
  int ia = atomicAdd(&deg[a], 1);
  nbr[a * CAP + ia] = (unsigned short)b;
  int ib = atomicAdd(&deg[b], 1);
  nbr[b * CAP + ib] = (unsigned short)a;
}

// ---------------- sortable keys: prio(double) top bits | edge id -----------
__global__ void k_keys(const double* __restrict__ sqd, const int* __restrict__ edges,
                       int E, int P, u64* __restrict__ keys) {
  int e = blockIdx.x * blockDim.x + threadIdx.x;
  if (e >= P) return;
  if (e < E) {
    double prio = sqd[edges[e]] + sqd[edges[E + e]];
    u64 bits = (u64)__double_as_longlong(prio);  // prio > 0 -> bits monotone
    keys[e] = (bits & ~0xFFFFull) | (u64)e;
  } else {
    keys[e] = ~0ull;
  }
}

// ---------------- single-block bitonic sort, LDS-staged --------------------
#define SCH 4096
__global__ void __launch_bounds__(1024)
k_sort(u64* __restrict__ keys, int n) {
  __shared__ u64 buf[SCH];
  int tid = threadIdx.x;
  int nt = blockDim.x;
  int ch = n < SCH ? n : SCH;
  for (int chunk = 0; chunk < n; chunk += ch) {
    for (int i = tid; i < ch; i += nt) buf[i] = keys[chunk + i];
    __syncthreads();
    for (int k = 2; k <= ch; k <<= 1) {
      for (int j = k >> 1; j > 0; j >>= 1) {
        for (int li = tid; li < ch; li += nt) {
          int lj = li ^ j;
          if (lj > li) {
            u64 x = buf[li], y = buf[lj];
            bool up = (((chunk + li) & k) == 0);
            if (up ? (x > y) : (x < y)) { buf[li] = y; buf[lj] = x; }
          }
        }
        __syncthreads();
      }
    }
    for (int i = tid; i < ch; i += nt) keys[chunk + i] = buf[i];
    __syncthreads();
  }
  for (int k = (ch << 1); k <= n; k <<= 1) {
    for (int j = k >> 1; j >= ch; j >>= 1) {
      for (int i = tid; i < n; i += nt) {
        int ixj = i ^ j;
        if (ixj > i) {
          u64 x = keys[i], y = keys[ixj];
          bool up = ((i & k) == 0);
          if (up ? (x > y) : (x < y)) { keys[i] = y; keys[ixj] = x; }
        }
      }
      __syncthreads();
    }
    for (int chunk = 0; chunk < n; chunk += ch) {
      for (int i = tid; i < ch; i += nt) buf[i] = keys[chunk + i];
      __syncthreads();
      for (int j = ch >> 1; j > 0; j >>= 1) {
        for (int li = tid; li < ch; li += nt) {
          int lj = li ^ j;
          if (lj > li) {
            u64 x = buf[li], y = buf[lj];
            bool up = (((chunk + li) & k) == 0);
            if (up ? (x > y) : (x < y)) { buf[li] = y; buf[lj] = x; }
          }
        }
        __syncthreads();
      }
      for (int i = tid; i < ch; i += nt) keys[chunk + i] = buf[i];
      __syncthreads();
    }
  }
}

// ---------------- gather sorted (v0,v1,elig) into one packed word ----------
__global__ void k_reorder(const u64* __restrict__ keys, const int* __restrict__ edges,
                          const unsigned char* __restrict__ elig, int E,
                          unsigned* __restrict__ packed) {
  int t = blockIdx.x * blockDim.x + threadIdx.x;
  if (t >= E) return;
  int eid = (int)(keys[t] & 0xFFFFull);
  unsigned v0 = (unsigned)edges[eid];
  unsigned v1 = (unsigned)edges[E + eid];
  unsigned el = (unsigned)elig[eid];
  packed[t] = v0 | (v1 << 14) | (el << 28);
}

// path-halving find on LDS union-find
__device__ __forceinline__ int findroot(unsigned short* ren, int x) {
  while (true) {
    int p = ren[x];
    if (p == x) return x;
    int q = ren[p];
    if (q == p) return p;
    ren[x] = (unsigned short)q;   // halving (benign; roots invariant)
    x = q;
  }
}

// ---------------- sequential greedy decimation (single wave, paired) -------
// R5 lazy-merge substrate. Two candidates evaluated per wave pass (lanes
// 0-31 = A, 32-63 = B) sharing one findroot + one marks round-trip. B's
// result is reused only if A's commit couldn't touch B's read-set; else B
// re-evaluates via the full-wave solo path (also used for degree > 32).
__global__ void __launch_bounds__(64, 1)
k_decimate(int E, int V, int target, const unsigned* __restrict__ packed,
           const int* __restrict__ deg_g, unsigned short* __restrict__ nbr,
           int2* __restrict__ events, int* __restrict__ nev_out) {
  __shared__ unsigned short ren[MAXV];
  __shared__ unsigned short rln[MAXV];
  __shared__ unsigned short mkA0[MAXV], mkB0[MAXV];
  __shared__ unsigned short mkA1[MAXV], mkB1[MAXV];
  const int lane = threadIdx.x;
  const int lane_h = lane & 31;
  if (V > MAXV) return;
  for (int v = lane; v < V; v += 64) {
    ren[v] = (unsigned short)v;
    rln[v] = (unsigned short)deg_g[v];
    mkA0[v] = 0; mkB0[v] = 0; mkA1[v] = 0; mkB1[v] = 0;
  }
  __syncthreads();

  int count = V, nev = 0;
  unsigned ctr = 0;
  bool stop = false, dirty = false;
  const u64 lanebit = 1ull << lane;
  const u64 below = lanebit - 1;

  auto bumpCtr = [&]() {
    ++ctr;
    if ((ctr & 1023u) == 0u) {
      for (int v = lane; v < MAXV; v += 64) { mkA0[v] = 0; mkB0[v] = 0; mkA1[v] = 0; mkB1[v] = 0; }
      asm volatile("s_waitcnt lgkmcnt(0)" ::: "memory");
      __builtin_amdgcn_sched_barrier(0);
      ++ctr;
    }
  };

  // full-wave fallback eval+commit (fresh state); returns committed
  auto solo = [&](int cv0, int cv1) -> bool {
    if (ren[cv0] != (unsigned short)cv0 || ren[cv1] != (unsigned short)cv1) return false;
    int L0 = rln[cv0], L1 = rln[cv1];
    if (dirty) {
      asm volatile("s_waitcnt vmcnt(0)" ::: "memory");
      __builtin_amdgcn_sched_barrier(0);
      dirty = false;
    }
    unsigned rawA = (lane < L0) ? (unsigned)nbr[cv0 * CAP + lane] : 0u;
    unsigned rawB = (lane < L1) ? (unsigned)nbr[cv1 * CAP + lane] : 0u;
    int rA = 0x7FFF, rB = 0x7FFF;
    if (lane < L0) rA = findroot(ren, (int)rawA);
    if (lane < L1) rB = findroot(ren, (int)rawB);
    bumpCtr();
    unsigned tag = ctr & 1023u;
    unsigned short enc = (unsigned short)((tag << 6) | (unsigned)lane);
    bool wA = (lane < L0) && (rA != cv0);
    bool wB = (lane < L1) && (rB != cv1);
    if (wA) mkA0[rA] = enc;
    if (wB) mkB0[rB] = enc;
    asm volatile("s_waitcnt lgkmcnt(0)" ::: "memory");
    __builtin_amdgcn_sched_barrier(0);
    bool canonA = wA && (mkA0[rA] == enc);
    bool canonB = wB && (mkB0[rB] == enc);
    bool sh = canonA && ((mkB0[rA] >> 6) == tag);
    if (__popcll(__ballot(sh)) != 2) return false;
    if (L0 + L1 <= CAP) {
      if (lane < L1) nbr[cv0 * CAP + L0 + lane] = (unsigned short)rB;
      if (lane == 0) rln[cv0] = (unsigned short)(L0 + L1);
    } else {
      bool pa = canonA && (rA != cv1);
      bool pb = canonB && (rB != cv0) && ((mkA0[rB] >> 6) != tag);
      u64 ma = __ballot(pa);
      u64 mb = __ballot(pb);
      int na = __popcll(ma);
      int tot = na + __popcll(mb);
      if (tot > CAP) tot = CAP;
      if (pa) nbr[cv0 * CAP + __popcll(ma & below)] = (unsigned short)rA;
      if (pb) {
        int pos = na + __popcll(mb & below);
        if (pos < CAP) nbr[cv0 * CAP + pos] = (unsigned short)rB;
      }
      if (lane == 0) rln[cv0] = (unsigned short)tot;
    }
    if (lane == 0) {
      ren[cv1] = (unsigned short)cv0;
      events[nev] = make_int2(cv0, cv1);
    }
    asm volatile("s_waitcnt lgkmcnt(0)" ::: "memory");
    __builtin_amdgcn_sched_barrier(0);
    return true;
  };

  for (int base = 0; base < E && !stop; base += 64) {
    int t = base + lane;
    unsigned pk = (t < E) ? packed[t] : 0u;
    int mv0 = (int)(pk & 0x3FFFu);
    int mv1 = (int)((pk >> 14) & 0x3FFFu);
    bool cand = (t < E) && ((pk >> 28) & 1u) &&
                (ren[mv0] == (unsigned short)mv0) &&
                (ren[mv1] == (unsigned short)mv1);
    u64 cm = __ballot(cand);

    while (cm != 0 && !stop) {
      // ---- pick GP pairs ----
      int c0A[GP], c1A[GP], c0B[GP], c1B[GP];
      unsigned ga[GP], gb[GP];
#pragma unroll
      for (int p = 0; p < GP; ++p) {
        int idA = -1, idB = -1;
        if (cm) { idA = __builtin_ctzll(cm); cm &= cm - 1; }
        if (cm) { idB = __builtin_ctzll(cm); cm &= cm - 1; }
        if (idA >= 0) {
          unsigned pkc = __builtin_amdgcn_readlane(pk, idA);
          c0A[p] = (int)(pkc & 0x3FFFu); c1A[p] = (int)((pkc >> 14) & 0x3FFFu);
        } else { c0A[p] = -1; c1A[p] = -1; }
        if (idB >= 0) {
          unsigned pkc = __builtin_amdgcn_readlane(pk, idB);
          c0B[p] = (int)(pkc & 0x3FFFu); c1B[p] = (int)((pkc >> 14) & 0x3FFFu);
        } else { c0B[p] = -1; c1B[p] = -1; }
      }
      if (dirty) {
        asm volatile("s_waitcnt vmcnt(0)" ::: "memory");
        __builtin_amdgcn_sched_barrier(0);
        dirty = false;
      }
#pragma unroll
      for (int p = 0; p < GP; ++p) {
        int cv0h = (lane < 32) ? c0A[p] : c0B[p];
        int cv1h = (lane < 32) ? c1A[p] : c1B[p];
        if (cv0h >= 0) {
          ga[p] = (unsigned)nbr[cv0h * CAP + lane_h];
          gb[p] = (unsigned)nbr[cv1h * CAP + lane_h];
        } else { ga[p] = 0; gb[p] = 0; }
      }
      int app[2 * GP];
#pragma unroll
      for (int j = 0; j < 2 * GP; ++j) app[j] = -1;

#pragma unroll
      for (int p = 0; p < GP; ++p) {
        if (c0A[p] < 0 || stop) continue;
        // staleness of prefetched rows vs earlier commits in this group
        bool stale = false;
#pragma unroll
        for (int j = 0; j < 2 * GP; ++j) {
          if (j < 2 * p && app[j] >= 0) {
            stale = stale || app[j] == c0A[p] || app[j] == c1A[p] ||
                             app[j] == c0B[p] || app[j] == c1B[p];
          }
        }
        if (stale) {
          asm volatile("s_waitcnt vmcnt(0)" ::: "memory");
          __builtin_amdgcn_sched_barrier(0);
          dirty = false;
          int cv0h = (lane < 32) ? c0A[p] : c0B[p];
          int cv1h = (lane < 32) ? c1A[p] : c1B[p];
          if (cv0h >= 0) {
            ga[p] = (unsigned)nbr[cv0h * CAP + lane_h];
            gb[p] = (unsigned)nbr[cv1h * CAP + lane_h];
          }
        }
        int cv0 = (lane < 32) ? c0A[p] : c0B[p];
        int cv1 = (lane < 32) ? c1A[p] : c1B[p];
        bool halfAct = cv0 >= 0;
        bool alive = halfAct && ren[cv0] == (unsigned short)cv0 &&
                                ren[cv1] == (unsigned short)cv1;
        int L0 = alive ? (int)rln[cv0] : 0;
        int L1 = alive ? (int)rln[cv1] : 0;
        bool paired = alive && L0 <= 32 && L1 <= 32;
        bool soloH = alive && !paired;
        u64 aliveBal = __ballot(alive);
        u64 soloBal = __ballot(soloH);
        // ---- shared eval: one findroot + one marks round-trip for 2 cands
        bumpCtr();
        unsigned tag = ctr & 1023u;
        int rA = 0x7FFF, rB = 0x7FFF;
        if (paired && lane_h < L0) rA = findroot(ren, (int)(ga[p] & 0xFFFFu));
        if (paired && lane_h < L1) rB = findroot(ren, (int)(gb[p] & 0xFFFFu));
        unsigned short* mA = (lane < 32) ? mkA0 : mkA1;
        unsigned short* mB = (lane < 32) ? mkB0 : mkB1;
        unsigned short enc = (unsigned short)((tag << 6) | (unsigned)lane);
        bool wA = paired && lane_h < L0 && rA != cv0;
        bool wB = paired && lane_h < L1 && rB != cv1;
        if (wA) mA[rA] = enc;
        if (wB) mB[rB] = enc;
        asm volatile("s_waitcnt lgkmcnt(0)" ::: "memory");
        __builtin_amdgcn_sched_barrier(0);
        bool sh = wA && (mA[rA] == enc) && ((mB[rA] >> 6) == tag);
        u64 shBal = __ballot(sh);
        int cntA = __popcll(shBal & 0xFFFFFFFFull);
        int cntB = __popcll(shBal >> 32);
        bool aliveA = (aliveBal & 1ull) != 0;
        bool aliveB = ((aliveBal >> 32) & 1ull) != 0;
        bool soloA = (soloBal & 1ull) != 0;
        bool soloB = ((soloBal >> 32) & 1ull) != 0;
        int L0A = __builtin_amdgcn_readlane(L0, 0);
        int L1A = __builtin_amdgcn_readlane(L1, 0);
        int L0B = __builtin_amdgcn_readlane(L0, 32);
        int L1B = __builtin_amdgcn_readlane(L1, 32);
        // ---- decide A (earlier slot) ----
        bool committedA = false;
        if (aliveA) {
          if (soloA) {
            committedA = solo(c0A[p], c1A[p]);
          } else if (cntA == 2) {
            if (lane < 32 && lane_h < L1A)
              nbr[c0A[p] * CAP + L0A + lane_h] = (unsigned short)rB;
            if (lane == 0) {
              rln[c0A[p]] = (unsigned short)(L0A + L1A);
              rln[c1A[p]] = 0;
              ren[c1A[p]] = (unsigned short)c0A[p];
              events[nev] = make_int2(c0A[p], c1A[p]);
            }
            asm volatile("s_waitcnt lgkmcnt(0)" ::: "memory");
            __builtin_amdgcn_sched_barrier(0);
            committedA = true;
          }
          if (committedA) {
            app[2 * p] = c0A[p];
            nev++; count--; dirty = true;
            if (count <= target) stop = true;
          }
        }
        // ---- decide B ----
        if (!stop && c0B[p] >= 0 && aliveB) {
          bool deadB = false, soloNeedB = soloB;
          if (committedA) {
            int c1a = c1A[p], c0a = c0A[p];
            if (c0B[p] == c1a || c1B[p] == c1a) deadB = true;   // endpoint died: final reject
            else {
              u64 hb = __ballot((rA == c1a) || (rB == c1a));    // cv1A among B's roots?
              if (c0B[p] == c0a || c1B[p] == c0a || (hb >> 32) != 0ull) soloNeedB = true;
            }
          }
          if (!deadB) {
            bool commitB = false;
            if (soloNeedB) {
              commitB = solo(c0B[p], c1B[p]);
            } else if (cntB == 2) {
              if (lane >= 32 && lane_h < L1B)
                nbr[c0B[p] * CAP + L0B + lane_h] = (unsigned short)rB;
              if (lane == 0) {
                rln[c0B[p]] = (unsigned short)(L0B + L1B);
                rln[c1B[p]] = 0;
                ren[c1B[p]] = (unsigned short)c0B[p];
                events[nev] = make_int2(c0B[p], c1B[p]);
              }
              asm volatile("s_waitcnt lgkmcnt(0)" ::: "memory");
              __builtin_amdgcn_sched_barrier(0);
              commitB = true;
            }
            if (commitB) {
              app[2 * p + 1] = c0B[p];
              nev++; count--; dirty = true;
              if (count <= target) stop = true;
            }
          }
        }
      }
    }
  }
  if (lane == 0) nev_out[0] = nev;
}

// ---------------- reverse-replay: owner + weight per original vertex -------
__global__ void __launch_bounds__(256)
k_weights(const int2* __restrict__ events, const int* __restrict__ nev_p,
          int V, int* __restrict__ own, float* __restrict__ wgt) {
  __shared__ int O[MAXV];
  __shared__ unsigned short H[MAXV];
  __shared__ int2 evb[256];
  int tid = threadIdx.x;
  if (V > MAXV) return;
  for (int v = tid; v < V; v += blockDim.x) { O[v] = v; H[v] = 0; }
  int n = nev_p[0];
  __syncthreads();
  int nb = (n + 255) >> 8;
  for (int b = nb - 1; b >= 0; --b) {
    int bbase = b << 8;
    int cnt = n - bbase; if (cnt > 256) cnt = 256;
    if (tid < cnt) evb[tid] = events[bbase + tid];
    __syncthreads();
    if (tid == 0) {
      for (int k = cnt - 1; k >= 0; --k) {
        int2 ev = evb[k];
        int h = (int)H[ev.x] + 1;
        H[ev.x] = (unsigned short)h;
        H[ev.y] = (unsigned short)h;
        O[ev.y] = O[ev.x];
      }
    }
    __syncthreads();
  }
  for (int v = tid; v < V; v += blockDim.x) {
    own[v] = O[v];
    wgt[v] = ldexpf(1.0f, -(int)H[v]);
  }
}

// ---------------- output ---------------------------------------------------
__global__ void k_zero(float4* __restrict__ out, int n4) {
  int i = blockIdx.x * blockDim.x + threadIdx.x;
  if (i < n4) out[i] = make_float4(0.f, 0.f, 0.f, 0.f);
}

__global__ void k_scatter(const float* __restrict__ img, const int* __restrict__ own,
                          const float* __restrict__ wgt, float* __restrict__ out, int V) {
  int v = blockIdx.x;
  if (v >= V) return;
  float w = wgt[v];
  int o = own[v];
  const float* src = img + (size_t)v * F_DIM;
  float* dst = out + (size_t)o * F_DIM;
  if (w == 1.0f) {
    for (int f = threadIdx.x; f < F_DIM; f += blockDim.x) dst[f] = src[f];
  } else {
    for (int f = threadIdx.x; f < F_DIM; f += blockDim.x) atomicAdd(&dst[f], w * src[f]);
  }
}

extern "C" void kernel_launch(void* const* d_in, const int* in_sizes, int n_in,
                              void* d_out, int out_size, void* d_ws, size_t ws_size,
                              hipStream_t stream) {
  const float* img  = (const float*)d_in[0];
  const int* edges  = (const int*)d_in[1];
  const float* vs   = (const float*)d_in[2];
  int V = in_sizes[2] / 2;
  int E = in_sizes[1] / 2;
  int P = 1; while (P < E) P <<= 1;

  char* wsp = (char*)d_ws;
  size_t off = 0;
  auto alloc = [&](size_t bytes) -> void* {
    void* p = (void*)(wsp + off);
    off = (off + bytes + 255) & ~(size_t)255;
    return p;
  };
  double* sqd          = (double*)alloc((size_t)V * 8);
  u64* keys            = (u64*)alloc((size_t)P * 8);
  int* deg             = (int*)alloc((size_t)V * 4);
  unsigned short* nbr  = (unsigned short*)alloc((size_t)V * CAP * 2 + 256);
  unsigned char* elig  = (unsigned char*)alloc((size_t)E);
  unsigned* packed     = (unsigned*)alloc((size_t)E * 4);
  int2* events         = (int2*)alloc((size_t)(V / 2 + 64) * 8);
  int* nev             = (int*)alloc(256);
  int* own             = (int*)alloc((size_t)V * 4);
  float* wgt           = (float*)alloc((size_t)V * 4);

  hipLaunchKernelGGL(k_sq, dim3(V), dim3(64), 0, stream, img, sqd, V);
  int mx = V > E ? V : E;
  hipLaunchKernelGGL(k_prep, dim3((mx + 255) / 256), dim3(256), 0, stream, vs, edges, V, E, deg, elig);
  hipLaunchKernelGGL(k_lists, dim3((E + 255) / 256), dim3(256), 0, stream, edges, E, deg, nbr);
  hipLaunchKernelGGL(k_keys, dim3((P + 255) / 256), dim3(256), 0, stream, sqd, edges, E, P, keys);
  hipLaunchKernelGGL(k_sort, dim3(1), dim3(1024), 0, stream, keys, P);
  hipLaunchKernelGGL(k_reorder, dim3((E + 255) / 256), dim3(256), 0, stream, keys, edges, elig, E, packed);
  hipLaunchKernelGGL(k_decimate, dim3(1), dim3(64), 0, stream,
                     E, V, V / 2, packed, deg, nbr, events, nev);
  hipLaunchKernelGGL(k_weights, dim3(1), dim3(256), 0, stream, events, nev, V, own, wgt);
  int n4 = (V * F_DIM) / 4;
  hipLaunchKernelGGL(k_zero, dim3((n4 + 255) / 256), dim3(256), 0, stream, (float4*)d_out, n4);
  hipLaunchKernelGGL(k_scatter, dim3(V), dim3(256), 0, stream, img, own, wgt, (float*)d_out, V);
}